// Round 1
// baseline (1197.974 us; speedup 1.0000x reference)
//
#include <hip/hip_runtime.h>

#define NEG_SLOPE 0.2f

// ---------------------------------------------------------------------------
// Utility kernels: CSR build (degree count, scan, scatter)
// ---------------------------------------------------------------------------

__global__ void fill_zero_kernel(int* __restrict__ p, int n) {
    int i = blockIdx.x * blockDim.x + threadIdx.x;
    if (i < n) p[i] = 0;
}

// Detect whether edge_index is int64 (flag=1) or int32 (flag=0).
// For little-endian int64 values in [0, N), every odd 32-bit word is zero.
__global__ void detect_i64_kernel(const unsigned int* __restrict__ w, int E, int* __restrict__ flag) {
    __shared__ unsigned int ssum[256];
    int n = E < 4096 ? E : 4096;
    unsigned int local = 0;
    for (int k = threadIdx.x; k < n; k += 256) local |= w[2 * k + 1];
    ssum[threadIdx.x] = local;
    __syncthreads();
    for (int off = 128; off > 0; off >>= 1) {
        if (threadIdx.x < off) ssum[threadIdx.x] |= ssum[threadIdx.x + off];
        __syncthreads();
    }
    if (threadIdx.x == 0) flag[0] = (ssum[0] == 0) ? 1 : 0;
}

__global__ void count_deg_kernel(const void* __restrict__ eiv, int E,
                                 const int* __restrict__ flag, int* __restrict__ deg) {
    int e = blockIdx.x * blockDim.x + threadIdx.x;
    if (e >= E) return;
    int d;
    if (*flag) d = (int)((const long long*)eiv)[(size_t)E + e];
    else       d = ((const int*)eiv)[(size_t)E + e];
    atomicAdd(&deg[d], 1);
}

// Single-block exclusive scan producing row_ptr[0..N] from deg[0..N-1].
__global__ void scan_kernel(const int* __restrict__ deg, int* __restrict__ row_ptr, int N) {
    __shared__ int sd[1024];
    __shared__ int srun;
    int t = threadIdx.x;
    if (t == 0) { srun = 0; row_ptr[0] = 0; }
    __syncthreads();
    for (int base = 0; base < N; base += 1024) {
        int v = (base + t < N) ? deg[base + t] : 0;
        sd[t] = v;
        __syncthreads();
        for (int off = 1; off < 1024; off <<= 1) {
            int add = (t >= off) ? sd[t - off] : 0;
            __syncthreads();
            sd[t] += add;
            __syncthreads();
        }
        if (base + t < N) row_ptr[base + t + 1] = srun + sd[t];
        __syncthreads();
        if (t == 0) srun += sd[1023];
        __syncthreads();
    }
}

__global__ void scatter_kernel(const void* __restrict__ eiv, int E,
                               const int* __restrict__ flag,
                               const int* __restrict__ row_ptr,
                               int* __restrict__ cursor, int* __restrict__ csr) {
    int e = blockIdx.x * blockDim.x + threadIdx.x;
    if (e >= E) return;
    int s, d;
    if (*flag) {
        s = (int)((const long long*)eiv)[e];
        d = (int)((const long long*)eiv)[(size_t)E + e];
    } else {
        s = ((const int*)eiv)[e];
        d = ((const int*)eiv)[(size_t)E + e];
    }
    int pos = atomicAdd(&cursor[d], 1);
    csr[row_ptr[d] + pos] = s;
}

// ---------------------------------------------------------------------------
// Fused dual GEMM: Cl = A @ Wl, Cr = A @ Wr
// A: [N, 256] row-major (stride 256). Wl/Wr: [256, M] row-major. M in {256, 64}.
// Block: 256 threads, 64x64 output tile, K-step 16.
// ---------------------------------------------------------------------------

__global__ __launch_bounds__(256) void gemm_fused_kernel(
    const float* __restrict__ A, const float* __restrict__ Wl, const float* __restrict__ Wr,
    float* __restrict__ Cl, float* __restrict__ Cr, int N, int M) {
    __shared__ float As[16][64];
    __shared__ float Bl[16][64];
    __shared__ float Br[16][64];

    int t = threadIdx.x;
    int row0 = blockIdx.x * 64;
    int n0 = blockIdx.y * 64;

    // load mappings
    int lr = t >> 2;             // 0..63: A-row within tile
    int lq = (t & 3) * 4;        // 0,4,8,12: k quad
    int wk = t >> 4;             // 0..15: W k-row
    int wc = (t & 15) * 4;       // 0..60: W col quad
    // compute mapping
    int cr = (t >> 4) * 4;       // 4 rows
    int cc = (t & 15) * 4;       // 4 cols

    float accL[4][4] = {};
    float accR[4][4] = {};

    for (int k0 = 0; k0 < 256; k0 += 16) {
        float4 av = make_float4(0.f, 0.f, 0.f, 0.f);
        int arow = row0 + lr;
        if (arow < N) av = *reinterpret_cast<const float4*>(&A[(size_t)arow * 256 + k0 + lq]);
        As[lq + 0][lr] = av.x;
        As[lq + 1][lr] = av.y;
        As[lq + 2][lr] = av.z;
        As[lq + 3][lr] = av.w;
        float4 blv = *reinterpret_cast<const float4*>(&Wl[(size_t)(k0 + wk) * M + n0 + wc]);
        float4 brv = *reinterpret_cast<const float4*>(&Wr[(size_t)(k0 + wk) * M + n0 + wc]);
        *reinterpret_cast<float4*>(&Bl[wk][wc]) = blv;
        *reinterpret_cast<float4*>(&Br[wk][wc]) = brv;
        __syncthreads();

        #pragma unroll
        for (int kk = 0; kk < 16; ++kk) {
            float a[4];
            #pragma unroll
            for (int r = 0; r < 4; ++r) a[r] = As[kk][cr + r];
            float4 bl4 = *reinterpret_cast<const float4*>(&Bl[kk][cc]);
            float4 br4 = *reinterpret_cast<const float4*>(&Br[kk][cc]);
            #pragma unroll
            for (int r = 0; r < 4; ++r) {
                accL[r][0] = fmaf(a[r], bl4.x, accL[r][0]);
                accL[r][1] = fmaf(a[r], bl4.y, accL[r][1]);
                accL[r][2] = fmaf(a[r], bl4.z, accL[r][2]);
                accL[r][3] = fmaf(a[r], bl4.w, accL[r][3]);
                accR[r][0] = fmaf(a[r], br4.x, accR[r][0]);
                accR[r][1] = fmaf(a[r], br4.y, accR[r][1]);
                accR[r][2] = fmaf(a[r], br4.z, accR[r][2]);
                accR[r][3] = fmaf(a[r], br4.w, accR[r][3]);
            }
        }
        __syncthreads();
    }

    #pragma unroll
    for (int r = 0; r < 4; ++r) {
        int row = row0 + cr + r;
        if (row < N) {
            *reinterpret_cast<float4*>(&Cl[(size_t)row * M + n0 + cc]) =
                make_float4(accL[r][0], accL[r][1], accL[r][2], accL[r][3]);
            *reinterpret_cast<float4*>(&Cr[(size_t)row * M + n0 + cc]) =
                make_float4(accR[r][0], accR[r][1], accR[r][2], accR[r][3]);
        }
    }
}

// ---------------------------------------------------------------------------
// Per-node edge aggregation with online softmax. Layers 1-2: H=8, C=32, D=256.
// One block (256 threads) per node; thread t owns (h = t>>5, c = t&31).
// ---------------------------------------------------------------------------

__global__ __launch_bounds__(256) void agg_h8_kernel(
    const float* __restrict__ xl, const float* __restrict__ xr,
    const float* __restrict__ att, const float* __restrict__ bias,
    const int* __restrict__ row_ptr, const int* __restrict__ csr,
    float* __restrict__ out, int N, int applyElu) {
    int i = blockIdx.x;
    int t = threadIdx.x;
    float rxr = xr[(size_t)i * 256 + t];
    float ratt = att[t];
    float b = bias[t];
    int start = row_ptr[i], end = row_ptr[i + 1];

    float m = -1e30f, l = 0.f, acc = 0.f;
    for (int k = start - 1; k < end; ++k) {
        int s = (k < start) ? i : csr[k];
        float sv = xl[(size_t)s * 256 + t];
        float v = sv + rxr;
        v = (v > 0.f) ? v : NEG_SLOPE * v;
        float p = v * ratt;
        // reduce over 32 lanes (one head)
        #pragma unroll
        for (int off = 16; off > 0; off >>= 1) p += __shfl_xor(p, off, 32);
        float logit = p;
        float nm = fmaxf(m, logit);
        float esc = __expf(m - nm);
        float pe = __expf(logit - nm);
        l = l * esc + pe;
        acc = acc * esc + pe * sv;
        m = nm;
    }
    float res = acc / l + b;
    if (applyElu) res = (res > 0.f) ? res : (__expf(res) - 1.0f);
    out[(size_t)i * 256 + t] = res;
}

// Layer 3: H=1, C=64. One wave (64 lanes) per node; 4 nodes per block.
__global__ __launch_bounds__(256) void agg_h1_kernel(
    const float* __restrict__ xl, const float* __restrict__ xr,
    const float* __restrict__ att, const float* __restrict__ bias,
    const int* __restrict__ row_ptr, const int* __restrict__ csr,
    float* __restrict__ out, int N) {
    int lane = threadIdx.x & 63;
    int wv = threadIdx.x >> 6;
    int i = blockIdx.x * 4 + wv;
    if (i >= N) return;
    float rxr = xr[(size_t)i * 64 + lane];
    float ratt = att[lane];
    float b = bias[lane];
    int start = row_ptr[i], end = row_ptr[i + 1];

    float m = -1e30f, l = 0.f, acc = 0.f;
    for (int k = start - 1; k < end; ++k) {
        int s = (k < start) ? i : csr[k];
        float sv = xl[(size_t)s * 64 + lane];
        float v = sv + rxr;
        v = (v > 0.f) ? v : NEG_SLOPE * v;
        float p = v * ratt;
        #pragma unroll
        for (int off = 32; off > 0; off >>= 1) p += __shfl_xor(p, off, 64);
        float nm = fmaxf(m, p);
        float esc = __expf(m - nm);
        float pe = __expf(p - nm);
        l = l * esc + pe;
        acc = acc * esc + pe * sv;
        m = nm;
    }
    out[(size_t)i * 64 + lane] = acc / l + b;
}

// ---------------------------------------------------------------------------

extern "C" void kernel_launch(void* const* d_in, const int* in_sizes, int n_in,
                              void* d_out, int out_size, void* d_ws, size_t ws_size,
                              hipStream_t stream) {
    const float* x    = (const float*)d_in[0];
    const void*  ei   = d_in[1];
    const float* Wl1  = (const float*)d_in[2];
    const float* Wr1  = (const float*)d_in[3];
    const float* att1 = (const float*)d_in[4];
    const float* b1   = (const float*)d_in[5];
    const float* Wl2  = (const float*)d_in[6];
    const float* Wr2  = (const float*)d_in[7];
    const float* att2 = (const float*)d_in[8];
    const float* b2   = (const float*)d_in[9];
    const float* Wl3  = (const float*)d_in[10];
    const float* Wr3  = (const float*)d_in[11];
    const float* att3 = (const float*)d_in[12];
    const float* b3   = (const float*)d_in[13];
    float* out = (float*)d_out;

    int N = in_sizes[0] / 256;
    int E = in_sizes[1] / 2;

    char* w = (char*)d_ws;
    float* xl = (float*)w; w += (size_t)N * 256 * sizeof(float);
    float* xr = (float*)w; w += (size_t)N * 256 * sizeof(float);
    float* h  = (float*)w; w += (size_t)N * 256 * sizeof(float);
    int* row_ptr = (int*)w; w += ((size_t)N + 2) * sizeof(int);
    int* deg     = (int*)w; w += (size_t)N * sizeof(int);
    int* csr     = (int*)w; w += (size_t)E * sizeof(int);
    int* flag    = (int*)w; w += 256;

    // --- CSR build (same graph for all 3 layers) ---
    detect_i64_kernel<<<1, 256, 0, stream>>>((const unsigned int*)ei, E, flag);
    fill_zero_kernel<<<(N + 255) / 256, 256, 0, stream>>>(deg, N);
    count_deg_kernel<<<(E + 255) / 256, 256, 0, stream>>>(ei, E, flag, deg);
    scan_kernel<<<1, 1024, 0, stream>>>(deg, row_ptr, N);
    fill_zero_kernel<<<(N + 255) / 256, 256, 0, stream>>>(deg, N);
    scatter_kernel<<<(E + 255) / 256, 256, 0, stream>>>(ei, E, flag, row_ptr, deg, csr);

    // --- Layer 1 ---
    dim3 g12((N + 63) / 64, 4);
    gemm_fused_kernel<<<g12, 256, 0, stream>>>(x, Wl1, Wr1, xl, xr, N, 256);
    agg_h8_kernel<<<N, 256, 0, stream>>>(xl, xr, att1, b1, row_ptr, csr, h, N, 1);

    // --- Layer 2 ---
    gemm_fused_kernel<<<g12, 256, 0, stream>>>(h, Wl2, Wr2, xl, xr, N, 256);
    agg_h8_kernel<<<N, 256, 0, stream>>>(xl, xr, att2, b2, row_ptr, csr, h, N, 1);

    // --- Layer 3 ---
    dim3 g3((N + 63) / 64, 1);
    gemm_fused_kernel<<<g3, 256, 0, stream>>>(h, Wl3, Wr3, xl, xr, N, 64);
    agg_h1_kernel<<<(N + 3) / 4, 256, 0, stream>>>(xl, xr, att3, b3, row_ptr, csr, out, N);
}

// Round 2
// 1013.873 us; speedup vs baseline: 1.1816x; 1.1816x over previous
//
#include <hip/hip_runtime.h>

#define NEG_SLOPE 0.2f

// ---------------------------------------------------------------------------
// Utility kernels: CSR build (degree count, scan, scatter)
// ---------------------------------------------------------------------------

__global__ void fill_zero_kernel(int* __restrict__ p, int n) {
    int i = blockIdx.x * blockDim.x + threadIdx.x;
    if (i < n) p[i] = 0;
}

// Detect whether edge_index is int64 (flag=1) or int32 (flag=0).
__global__ void detect_i64_kernel(const unsigned int* __restrict__ w, int E, int* __restrict__ flag) {
    __shared__ unsigned int ssum[256];
    int n = E < 4096 ? E : 4096;
    unsigned int local = 0;
    for (int k = threadIdx.x; k < n; k += 256) local |= w[2 * k + 1];
    ssum[threadIdx.x] = local;
    __syncthreads();
    for (int off = 128; off > 0; off >>= 1) {
        if (threadIdx.x < off) ssum[threadIdx.x] |= ssum[threadIdx.x + off];
        __syncthreads();
    }
    if (threadIdx.x == 0) flag[0] = (ssum[0] == 0) ? 1 : 0;
}

__global__ void count_deg_kernel(const void* __restrict__ eiv, int E,
                                 const int* __restrict__ flag, int* __restrict__ deg) {
    int e = blockIdx.x * blockDim.x + threadIdx.x;
    if (e >= E) return;
    int d;
    if (*flag) d = (int)((const long long*)eiv)[(size_t)E + e];
    else       d = ((const int*)eiv)[(size_t)E + e];
    atomicAdd(&deg[d], 1);
}

// Single-block exclusive scan producing row_ptr[0..N] from deg[0..N-1].
__global__ void scan_kernel(const int* __restrict__ deg, int* __restrict__ row_ptr, int N) {
    __shared__ int sd[1024];
    __shared__ int srun;
    int t = threadIdx.x;
    if (t == 0) { srun = 0; row_ptr[0] = 0; }
    __syncthreads();
    for (int base = 0; base < N; base += 1024) {
        int v = (base + t < N) ? deg[base + t] : 0;
        sd[t] = v;
        __syncthreads();
        for (int off = 1; off < 1024; off <<= 1) {
            int add = (t >= off) ? sd[t - off] : 0;
            __syncthreads();
            sd[t] += add;
            __syncthreads();
        }
        if (base + t < N) row_ptr[base + t + 1] = srun + sd[t];
        __syncthreads();
        if (t == 0) srun += sd[1023];
        __syncthreads();
    }
}

__global__ void scatter_kernel(const void* __restrict__ eiv, int E,
                               const int* __restrict__ flag,
                               const int* __restrict__ row_ptr,
                               int* __restrict__ cursor, int* __restrict__ csr) {
    int e = blockIdx.x * blockDim.x + threadIdx.x;
    if (e >= E) return;
    int s, d;
    if (*flag) {
        s = (int)((const long long*)eiv)[e];
        d = (int)((const long long*)eiv)[(size_t)E + e];
    } else {
        s = ((const int*)eiv)[e];
        d = ((const int*)eiv)[(size_t)E + e];
    }
    int pos = atomicAdd(&cursor[d], 1);
    csr[row_ptr[d] + pos] = s;
}

// ---------------------------------------------------------------------------
// Fused dual GEMM: Cl = A @ Wl, Cr = A @ Wr
// ---------------------------------------------------------------------------

__global__ __launch_bounds__(256) void gemm_fused_kernel(
    const float* __restrict__ A, const float* __restrict__ Wl, const float* __restrict__ Wr,
    float* __restrict__ Cl, float* __restrict__ Cr, int N, int M) {
    __shared__ float As[16][64];
    __shared__ float Bl[16][64];
    __shared__ float Br[16][64];

    int t = threadIdx.x;
    int row0 = blockIdx.x * 64;
    int n0 = blockIdx.y * 64;

    int lr = t >> 2;
    int lq = (t & 3) * 4;
    int wk = t >> 4;
    int wc = (t & 15) * 4;
    int cr = (t >> 4) * 4;
    int cc = (t & 15) * 4;

    float accL[4][4] = {};
    float accR[4][4] = {};

    for (int k0 = 0; k0 < 256; k0 += 16) {
        float4 av = make_float4(0.f, 0.f, 0.f, 0.f);
        int arow = row0 + lr;
        if (arow < N) av = *reinterpret_cast<const float4*>(&A[(size_t)arow * 256 + k0 + lq]);
        As[lq + 0][lr] = av.x;
        As[lq + 1][lr] = av.y;
        As[lq + 2][lr] = av.z;
        As[lq + 3][lr] = av.w;
        float4 blv = *reinterpret_cast<const float4*>(&Wl[(size_t)(k0 + wk) * M + n0 + wc]);
        float4 brv = *reinterpret_cast<const float4*>(&Wr[(size_t)(k0 + wk) * M + n0 + wc]);
        *reinterpret_cast<float4*>(&Bl[wk][wc]) = blv;
        *reinterpret_cast<float4*>(&Br[wk][wc]) = brv;
        __syncthreads();

        #pragma unroll
        for (int kk = 0; kk < 16; ++kk) {
            float a[4];
            #pragma unroll
            for (int r = 0; r < 4; ++r) a[r] = As[kk][cr + r];
            float4 bl4 = *reinterpret_cast<const float4*>(&Bl[kk][cc]);
            float4 br4 = *reinterpret_cast<const float4*>(&Br[kk][cc]);
            #pragma unroll
            for (int r = 0; r < 4; ++r) {
                accL[r][0] = fmaf(a[r], bl4.x, accL[r][0]);
                accL[r][1] = fmaf(a[r], bl4.y, accL[r][1]);
                accL[r][2] = fmaf(a[r], bl4.z, accL[r][2]);
                accL[r][3] = fmaf(a[r], bl4.w, accL[r][3]);
                accR[r][0] = fmaf(a[r], br4.x, accR[r][0]);
                accR[r][1] = fmaf(a[r], br4.y, accR[r][1]);
                accR[r][2] = fmaf(a[r], br4.z, accR[r][2]);
                accR[r][3] = fmaf(a[r], br4.w, accR[r][3]);
            }
        }
        __syncthreads();
    }

    #pragma unroll
    for (int r = 0; r < 4; ++r) {
        int row = row0 + cr + r;
        if (row < N) {
            *reinterpret_cast<float4*>(&Cl[(size_t)row * M + n0 + cc]) =
                make_float4(accL[r][0], accL[r][1], accL[r][2], accL[r][3]);
            *reinterpret_cast<float4*>(&Cr[(size_t)row * M + n0 + cc]) =
                make_float4(accR[r][0], accR[r][1], accR[r][2], accR[r][3]);
        }
    }
}

// ---------------------------------------------------------------------------
// Per-node edge aggregation, online softmax, 4-edge-chunked for ILP.
// Layers 1-2: H=8, C=32, D=256. One block (256 threads) per node.
// ---------------------------------------------------------------------------

__global__ __launch_bounds__(256) void agg_h8_kernel(
    const float* __restrict__ xl, const float* __restrict__ xr,
    const float* __restrict__ att, const float* __restrict__ bias,
    const int* __restrict__ row_ptr, const int* __restrict__ csr,
    float* __restrict__ out, int N, int applyElu) {
    int i = blockIdx.x;
    int t = threadIdx.x;
    float rxr = xr[(size_t)i * 256 + t];
    float ratt = att[t];
    int start = row_ptr[i], end = row_ptr[i + 1];

    // self-loop as initialization: pe = exp(p - m) = 1
    float svi = xl[(size_t)i * 256 + t];
    float vi = svi + rxr;
    vi = (vi > 0.f) ? vi : NEG_SLOPE * vi;
    float p = vi * ratt;
    #pragma unroll
    for (int off = 16; off > 0; off >>= 1) p += __shfl_xor(p, off, 32);
    float m = p, l = 1.f, acc = svi;

    for (int k = start; k < end; k += 4) {
        int n = end - k;  // >= 1
        int s0 = csr[k];
        int s1 = (n > 1) ? csr[k + 1] : s0;
        int s2 = (n > 2) ? csr[k + 2] : s0;
        int s3 = (n > 3) ? csr[k + 3] : s0;
        float sv0 = xl[(size_t)s0 * 256 + t];
        float sv1 = xl[(size_t)s1 * 256 + t];
        float sv2 = xl[(size_t)s2 * 256 + t];
        float sv3 = xl[(size_t)s3 * 256 + t];
        float v0 = sv0 + rxr; v0 = (v0 > 0.f) ? v0 : NEG_SLOPE * v0;
        float v1 = sv1 + rxr; v1 = (v1 > 0.f) ? v1 : NEG_SLOPE * v1;
        float v2 = sv2 + rxr; v2 = (v2 > 0.f) ? v2 : NEG_SLOPE * v2;
        float v3 = sv3 + rxr; v3 = (v3 > 0.f) ? v3 : NEG_SLOPE * v3;
        float p0 = v0 * ratt, p1 = v1 * ratt, p2 = v2 * ratt, p3 = v3 * ratt;
        // 4 interleaved independent reduce chains over the 32-lane head group
        #pragma unroll
        for (int off = 16; off > 0; off >>= 1) {
            p0 += __shfl_xor(p0, off, 32);
            p1 += __shfl_xor(p1, off, 32);
            p2 += __shfl_xor(p2, off, 32);
            p3 += __shfl_xor(p3, off, 32);
        }
        if (n < 2) p1 = -1e30f;
        if (n < 3) p2 = -1e30f;
        if (n < 4) p3 = -1e30f;
        // tree-combine the chunk, then single merge with running state
        float m4 = fmaxf(fmaxf(p0, p1), fmaxf(p2, p3));
        float e0 = __expf(p0 - m4);
        float e1 = __expf(p1 - m4);
        float e2 = __expf(p2 - m4);
        float e3 = __expf(p3 - m4);
        float l4 = (e0 + e1) + (e2 + e3);
        float a4 = fmaf(e0, sv0, e1 * sv1) + fmaf(e2, sv2, e3 * sv3);
        float nm = fmaxf(m, m4);
        float es = __expf(m - nm);
        float e4 = __expf(m4 - nm);
        l = fmaf(l, es, l4 * e4);
        acc = fmaf(acc, es, a4 * e4);
        m = nm;
    }
    float res = acc / l + bias[t];
    if (applyElu) res = (res > 0.f) ? res : (__expf(res) - 1.0f);
    out[(size_t)i * 256 + t] = res;
}

// Layer 3: H=1, C=64. One wave per node; 4 nodes per block.
__global__ __launch_bounds__(256) void agg_h1_kernel(
    const float* __restrict__ xl, const float* __restrict__ xr,
    const float* __restrict__ att, const float* __restrict__ bias,
    const int* __restrict__ row_ptr, const int* __restrict__ csr,
    float* __restrict__ out, int N) {
    int lane = threadIdx.x & 63;
    int wv = threadIdx.x >> 6;
    int i = blockIdx.x * 4 + wv;
    if (i >= N) return;
    float rxr = xr[(size_t)i * 64 + lane];
    float ratt = att[lane];
    int start = row_ptr[i], end = row_ptr[i + 1];

    float svi = xl[(size_t)i * 64 + lane];
    float vi = svi + rxr;
    vi = (vi > 0.f) ? vi : NEG_SLOPE * vi;
    float p = vi * ratt;
    #pragma unroll
    for (int off = 32; off > 0; off >>= 1) p += __shfl_xor(p, off, 64);
    float m = p, l = 1.f, acc = svi;

    for (int k = start; k < end; k += 4) {
        int n = end - k;
        int s0 = csr[k];
        int s1 = (n > 1) ? csr[k + 1] : s0;
        int s2 = (n > 2) ? csr[k + 2] : s0;
        int s3 = (n > 3) ? csr[k + 3] : s0;
        float sv0 = xl[(size_t)s0 * 64 + lane];
        float sv1 = xl[(size_t)s1 * 64 + lane];
        float sv2 = xl[(size_t)s2 * 64 + lane];
        float sv3 = xl[(size_t)s3 * 64 + lane];
        float v0 = sv0 + rxr; v0 = (v0 > 0.f) ? v0 : NEG_SLOPE * v0;
        float v1 = sv1 + rxr; v1 = (v1 > 0.f) ? v1 : NEG_SLOPE * v1;
        float v2 = sv2 + rxr; v2 = (v2 > 0.f) ? v2 : NEG_SLOPE * v2;
        float v3 = sv3 + rxr; v3 = (v3 > 0.f) ? v3 : NEG_SLOPE * v3;
        float p0 = v0 * ratt, p1 = v1 * ratt, p2 = v2 * ratt, p3 = v3 * ratt;
        #pragma unroll
        for (int off = 32; off > 0; off >>= 1) {
            p0 += __shfl_xor(p0, off, 64);
            p1 += __shfl_xor(p1, off, 64);
            p2 += __shfl_xor(p2, off, 64);
            p3 += __shfl_xor(p3, off, 64);
        }
        if (n < 2) p1 = -1e30f;
        if (n < 3) p2 = -1e30f;
        if (n < 4) p3 = -1e30f;
        float m4 = fmaxf(fmaxf(p0, p1), fmaxf(p2, p3));
        float e0 = __expf(p0 - m4);
        float e1 = __expf(p1 - m4);
        float e2 = __expf(p2 - m4);
        float e3 = __expf(p3 - m4);
        float l4 = (e0 + e1) + (e2 + e3);
        float a4 = fmaf(e0, sv0, e1 * sv1) + fmaf(e2, sv2, e3 * sv3);
        float nm = fmaxf(m, m4);
        float es = __expf(m - nm);
        float e4 = __expf(m4 - nm);
        l = fmaf(l, es, l4 * e4);
        acc = fmaf(acc, es, a4 * e4);
        m = nm;
    }
    out[(size_t)i * 64 + lane] = acc / l + bias[lane];
}

// ---------------------------------------------------------------------------

extern "C" void kernel_launch(void* const* d_in, const int* in_sizes, int n_in,
                              void* d_out, int out_size, void* d_ws, size_t ws_size,
                              hipStream_t stream) {
    const float* x    = (const float*)d_in[0];
    const void*  ei   = d_in[1];
    const float* Wl1  = (const float*)d_in[2];
    const float* Wr1  = (const float*)d_in[3];
    const float* att1 = (const float*)d_in[4];
    const float* b1   = (const float*)d_in[5];
    const float* Wl2  = (const float*)d_in[6];
    const float* Wr2  = (const float*)d_in[7];
    const float* att2 = (const float*)d_in[8];
    const float* b2   = (const float*)d_in[9];
    const float* Wl3  = (const float*)d_in[10];
    const float* Wr3  = (const float*)d_in[11];
    const float* att3 = (const float*)d_in[12];
    const float* b3   = (const float*)d_in[13];
    float* out = (float*)d_out;

    int N = in_sizes[0] / 256;
    int E = in_sizes[1] / 2;

    char* w = (char*)d_ws;
    float* xl = (float*)w; w += (size_t)N * 256 * sizeof(float);
    float* xr = (float*)w; w += (size_t)N * 256 * sizeof(float);
    float* h  = (float*)w; w += (size_t)N * 256 * sizeof(float);
    int* row_ptr = (int*)w; w += ((size_t)N + 2) * sizeof(int);
    int* deg     = (int*)w; w += (size_t)N * sizeof(int);
    int* csr     = (int*)w; w += (size_t)E * sizeof(int);
    int* flag    = (int*)w; w += 256;

    // --- CSR build (same graph for all 3 layers) ---
    detect_i64_kernel<<<1, 256, 0, stream>>>((const unsigned int*)ei, E, flag);
    fill_zero_kernel<<<(N + 255) / 256, 256, 0, stream>>>(deg, N);
    count_deg_kernel<<<(E + 255) / 256, 256, 0, stream>>>(ei, E, flag, deg);
    scan_kernel<<<1, 1024, 0, stream>>>(deg, row_ptr, N);
    fill_zero_kernel<<<(N + 255) / 256, 256, 0, stream>>>(deg, N);
    scatter_kernel<<<(E + 255) / 256, 256, 0, stream>>>(ei, E, flag, row_ptr, deg, csr);

    // --- Layer 1 ---
    dim3 g12((N + 63) / 64, 4);
    gemm_fused_kernel<<<g12, 256, 0, stream>>>(x, Wl1, Wr1, xl, xr, N, 256);
    agg_h8_kernel<<<N, 256, 0, stream>>>(xl, xr, att1, b1, row_ptr, csr, h, N, 1);

    // --- Layer 2 ---
    gemm_fused_kernel<<<g12, 256, 0, stream>>>(h, Wl2, Wr2, xl, xr, N, 256);
    agg_h8_kernel<<<N, 256, 0, stream>>>(xl, xr, att2, b2, row_ptr, csr, h, N, 1);

    // --- Layer 3 ---
    dim3 g3((N + 63) / 64, 1);
    gemm_fused_kernel<<<g3, 256, 0, stream>>>(h, Wl3, Wr3, xl, xr, N, 64);
    agg_h1_kernel<<<(N + 3) / 4, 256, 0, stream>>>(xl, xr, att3, b3, row_ptr, csr, out, N);
}

// Round 3
// 879.227 us; speedup vs baseline: 1.3625x; 1.1531x over previous
//
#include <hip/hip_runtime.h>

#define NEG_SLOPE 0.2f

// ---------------------------------------------------------------------------
// Utility kernels: CSR build (degree count, scan, scatter)
// ---------------------------------------------------------------------------

__global__ void fill_zero_kernel(int* __restrict__ p, int n) {
    int i = blockIdx.x * blockDim.x + threadIdx.x;
    if (i < n) p[i] = 0;
}

// Detect whether edge_index is int64 (flag=1) or int32 (flag=0).
__global__ void detect_i64_kernel(const unsigned int* __restrict__ w, int E, int* __restrict__ flag) {
    __shared__ unsigned int ssum[256];
    int n = E < 4096 ? E : 4096;
    unsigned int local = 0;
    for (int k = threadIdx.x; k < n; k += 256) local |= w[2 * k + 1];
    ssum[threadIdx.x] = local;
    __syncthreads();
    for (int off = 128; off > 0; off >>= 1) {
        if (threadIdx.x < off) ssum[threadIdx.x] |= ssum[threadIdx.x + off];
        __syncthreads();
    }
    if (threadIdx.x == 0) flag[0] = (ssum[0] == 0) ? 1 : 0;
}

__global__ void count_deg_kernel(const void* __restrict__ eiv, int E,
                                 const int* __restrict__ flag, int* __restrict__ deg) {
    int e = blockIdx.x * blockDim.x + threadIdx.x;
    if (e >= E) return;
    int d;
    if (*flag) d = (int)((const long long*)eiv)[(size_t)E + e];
    else       d = ((const int*)eiv)[(size_t)E + e];
    atomicAdd(&deg[d], 1);
}

// Single-block exclusive scan producing row_ptr[0..N] from deg[0..N-1].
__global__ void scan_kernel(const int* __restrict__ deg, int* __restrict__ row_ptr, int N) {
    __shared__ int sd[1024];
    __shared__ int srun;
    int t = threadIdx.x;
    if (t == 0) { srun = 0; row_ptr[0] = 0; }
    __syncthreads();
    for (int base = 0; base < N; base += 1024) {
        int v = (base + t < N) ? deg[base + t] : 0;
        sd[t] = v;
        __syncthreads();
        for (int off = 1; off < 1024; off <<= 1) {
            int add = (t >= off) ? sd[t - off] : 0;
            __syncthreads();
            sd[t] += add;
            __syncthreads();
        }
        if (base + t < N) row_ptr[base + t + 1] = srun + sd[t];
        __syncthreads();
        if (t == 0) srun += sd[1023];
        __syncthreads();
    }
}

__global__ void scatter_kernel(const void* __restrict__ eiv, int E,
                               const int* __restrict__ flag,
                               const int* __restrict__ row_ptr,
                               int* __restrict__ cursor, int* __restrict__ csr) {
    int e = blockIdx.x * blockDim.x + threadIdx.x;
    if (e >= E) return;
    int s, d;
    if (*flag) {
        s = (int)((const long long*)eiv)[e];
        d = (int)((const long long*)eiv)[(size_t)E + e];
    } else {
        s = ((const int*)eiv)[e];
        d = ((const int*)eiv)[(size_t)E + e];
    }
    int pos = atomicAdd(&cursor[d], 1);
    csr[row_ptr[d] + pos] = s;
}

// ---------------------------------------------------------------------------
// Fused dual GEMM: Cl = A @ Wl, Cr = A @ Wr
// ---------------------------------------------------------------------------

__global__ __launch_bounds__(256) void gemm_fused_kernel(
    const float* __restrict__ A, const float* __restrict__ Wl, const float* __restrict__ Wr,
    float* __restrict__ Cl, float* __restrict__ Cr, int N, int M) {
    __shared__ float As[16][64];
    __shared__ float Bl[16][64];
    __shared__ float Br[16][64];

    int t = threadIdx.x;
    int row0 = blockIdx.x * 64;
    int n0 = blockIdx.y * 64;

    int lr = t >> 2;
    int lq = (t & 3) * 4;
    int wk = t >> 4;
    int wc = (t & 15) * 4;
    int cr = (t >> 4) * 4;
    int cc = (t & 15) * 4;

    float accL[4][4] = {};
    float accR[4][4] = {};

    for (int k0 = 0; k0 < 256; k0 += 16) {
        float4 av = make_float4(0.f, 0.f, 0.f, 0.f);
        int arow = row0 + lr;
        if (arow < N) av = *reinterpret_cast<const float4*>(&A[(size_t)arow * 256 + k0 + lq]);
        As[lq + 0][lr] = av.x;
        As[lq + 1][lr] = av.y;
        As[lq + 2][lr] = av.z;
        As[lq + 3][lr] = av.w;
        float4 blv = *reinterpret_cast<const float4*>(&Wl[(size_t)(k0 + wk) * M + n0 + wc]);
        float4 brv = *reinterpret_cast<const float4*>(&Wr[(size_t)(k0 + wk) * M + n0 + wc]);
        *reinterpret_cast<float4*>(&Bl[wk][wc]) = blv;
        *reinterpret_cast<float4*>(&Br[wk][wc]) = brv;
        __syncthreads();

        #pragma unroll
        for (int kk = 0; kk < 16; ++kk) {
            float a[4];
            #pragma unroll
            for (int r = 0; r < 4; ++r) a[r] = As[kk][cr + r];
            float4 bl4 = *reinterpret_cast<const float4*>(&Bl[kk][cc]);
            float4 br4 = *reinterpret_cast<const float4*>(&Br[kk][cc]);
            #pragma unroll
            for (int r = 0; r < 4; ++r) {
                accL[r][0] = fmaf(a[r], bl4.x, accL[r][0]);
                accL[r][1] = fmaf(a[r], bl4.y, accL[r][1]);
                accL[r][2] = fmaf(a[r], bl4.z, accL[r][2]);
                accL[r][3] = fmaf(a[r], bl4.w, accL[r][3]);
                accR[r][0] = fmaf(a[r], br4.x, accR[r][0]);
                accR[r][1] = fmaf(a[r], br4.y, accR[r][1]);
                accR[r][2] = fmaf(a[r], br4.z, accR[r][2]);
                accR[r][3] = fmaf(a[r], br4.w, accR[r][3]);
            }
        }
        __syncthreads();
    }

    #pragma unroll
    for (int r = 0; r < 4; ++r) {
        int row = row0 + cr + r;
        if (row < N) {
            *reinterpret_cast<float4*>(&Cl[(size_t)row * M + n0 + cc]) =
                make_float4(accL[r][0], accL[r][1], accL[r][2], accL[r][3]);
            *reinterpret_cast<float4*>(&Cr[(size_t)row * M + n0 + cc]) =
                make_float4(accR[r][0], accR[r][1], accR[r][2], accR[r][3]);
        }
    }
}

// ---------------------------------------------------------------------------
// agg_h8 v3: one block (4 waves) per node. Lane lam owns channels 4*lam..4*lam+3
// (= head h=lam>>3, inner 4*(lam&7)..). Each wave processes a disjoint 1/4 of
// the incoming edges (stride-4 interleave, chunks of 4), keeping private
// per-head (m,l) and a full-row float4 accumulator. LDS tree-merge at end.
// ---------------------------------------------------------------------------

__device__ __forceinline__ float lrelu_dot4(const float4 sv, const float4 rxr, const float4 a) {
    float v0 = sv.x + rxr.x; v0 = (v0 > 0.f) ? v0 : NEG_SLOPE * v0;
    float v1 = sv.y + rxr.y; v1 = (v1 > 0.f) ? v1 : NEG_SLOPE * v1;
    float v2 = sv.z + rxr.z; v2 = (v2 > 0.f) ? v2 : NEG_SLOPE * v2;
    float v3 = sv.w + rxr.w; v3 = (v3 > 0.f) ? v3 : NEG_SLOPE * v3;
    return fmaf(v0, a.x, fmaf(v1, a.y, fmaf(v2, a.z, v3 * a.w)));
}

__global__ __launch_bounds__(256) void agg_h8_kernel(
    const float* __restrict__ xl, const float* __restrict__ xr,
    const float* __restrict__ att, const float* __restrict__ bias,
    const int* __restrict__ row_ptr, const int* __restrict__ csr,
    float* __restrict__ out, int N, int applyElu) {
    int i = blockIdx.x;
    int t = threadIdx.x;
    int w = t >> 6;
    int lam = t & 63;
    int o = lam * 4;           // channel offset of this lane's float4
    int h = lam >> 3;          // head

    const float4 rxr = *reinterpret_cast<const float4*>(&xr[(size_t)i * 256 + o]);
    const float4 at4 = *reinterpret_cast<const float4*>(&att[o]);
    int start = row_ptr[i], end = row_ptr[i + 1];

    float m, l;
    float4 acc;
    if (w == 0) {
        // self-loop as initialization
        float4 svi = *reinterpret_cast<const float4*>(&xl[(size_t)i * 256 + o]);
        float p = lrelu_dot4(svi, rxr, at4);
        #pragma unroll
        for (int off = 4; off > 0; off >>= 1) p += __shfl_xor(p, off, 8);
        m = p; l = 1.f; acc = svi;
    } else {
        m = -1e30f; l = 0.f; acc = make_float4(0.f, 0.f, 0.f, 0.f);
    }

    // wave w processes edges start+w, start+w+4, ... in chunks of 4
    for (int k = start + w; k < end; k += 16) {
        int s0 = csr[k];
        int s1 = (k + 4  < end) ? csr[k + 4]  : s0;
        int s2 = (k + 8  < end) ? csr[k + 8]  : s0;
        int s3 = (k + 12 < end) ? csr[k + 12] : s0;
        float4 sv0 = *reinterpret_cast<const float4*>(&xl[(size_t)s0 * 256 + o]);
        float4 sv1 = *reinterpret_cast<const float4*>(&xl[(size_t)s1 * 256 + o]);
        float4 sv2 = *reinterpret_cast<const float4*>(&xl[(size_t)s2 * 256 + o]);
        float4 sv3 = *reinterpret_cast<const float4*>(&xl[(size_t)s3 * 256 + o]);
        float p0 = lrelu_dot4(sv0, rxr, at4);
        float p1 = lrelu_dot4(sv1, rxr, at4);
        float p2 = lrelu_dot4(sv2, rxr, at4);
        float p3 = lrelu_dot4(sv3, rxr, at4);
        // 4 interleaved butterfly chains over the 8-lane head group
        #pragma unroll
        for (int off = 4; off > 0; off >>= 1) {
            p0 += __shfl_xor(p0, off, 8);
            p1 += __shfl_xor(p1, off, 8);
            p2 += __shfl_xor(p2, off, 8);
            p3 += __shfl_xor(p3, off, 8);
        }
        if (k + 4  >= end) p1 = -1e30f;
        if (k + 8  >= end) p2 = -1e30f;
        if (k + 12 >= end) p3 = -1e30f;
        float m4 = fmaxf(fmaxf(p0, p1), fmaxf(p2, p3));
        float e0 = __expf(p0 - m4);
        float e1 = __expf(p1 - m4);
        float e2 = __expf(p2 - m4);
        float e3 = __expf(p3 - m4);
        float l4 = (e0 + e1) + (e2 + e3);
        float nm = fmaxf(m, m4);
        float es = __expf(m - nm);
        float e4 = __expf(m4 - nm);
        l = fmaf(l, es, l4 * e4);
        acc.x = fmaf(acc.x, es, (fmaf(e0, sv0.x, e1 * sv1.x) + fmaf(e2, sv2.x, e3 * sv3.x)) * e4);
        acc.y = fmaf(acc.y, es, (fmaf(e0, sv0.y, e1 * sv1.y) + fmaf(e2, sv2.y, e3 * sv3.y)) * e4);
        acc.z = fmaf(acc.z, es, (fmaf(e0, sv0.z, e1 * sv1.z) + fmaf(e2, sv2.z, e3 * sv3.z)) * e4);
        acc.w = fmaf(acc.w, es, (fmaf(e0, sv0.w, e1 * sv1.w) + fmaf(e2, sv2.w, e3 * sv3.w)) * e4);
        m = nm;
    }

    // LDS merge of the 4 wave partials
    __shared__ float sm[4][8];
    __shared__ float sl[4][8];
    __shared__ float sacc[4][256];
    if ((lam & 7) == 0) { sm[w][h] = m; sl[w][h] = l; }
    *reinterpret_cast<float4*>(&sacc[w][o]) = acc;
    __syncthreads();

    int hh = t >> 5;  // head of output channel t
    float M = fmaxf(fmaxf(sm[0][hh], sm[1][hh]), fmaxf(sm[2][hh], sm[3][hh]));
    float ew0 = __expf(sm[0][hh] - M);
    float ew1 = __expf(sm[1][hh] - M);
    float ew2 = __expf(sm[2][hh] - M);
    float ew3 = __expf(sm[3][hh] - M);
    float den = fmaf(ew0, sl[0][hh], ew1 * sl[1][hh]) + fmaf(ew2, sl[2][hh], ew3 * sl[3][hh]);
    float num = fmaf(ew0, sacc[0][t], ew1 * sacc[1][t]) + fmaf(ew2, sacc[2][t], ew3 * sacc[3][t]);
    float res = num / den + bias[t];
    if (applyElu) res = (res > 0.f) ? res : (__expf(res) - 1.0f);
    out[(size_t)i * 256 + t] = res;
}

// Layer 3: H=1, C=64. One wave per node; 4 nodes per block.
__global__ __launch_bounds__(256) void agg_h1_kernel(
    const float* __restrict__ xl, const float* __restrict__ xr,
    const float* __restrict__ att, const float* __restrict__ bias,
    const int* __restrict__ row_ptr, const int* __restrict__ csr,
    float* __restrict__ out, int N) {
    int lane = threadIdx.x & 63;
    int wv = threadIdx.x >> 6;
    int i = blockIdx.x * 4 + wv;
    if (i >= N) return;
    float rxr = xr[(size_t)i * 64 + lane];
    float ratt = att[lane];
    int start = row_ptr[i], end = row_ptr[i + 1];

    float svi = xl[(size_t)i * 64 + lane];
    float vi = svi + rxr;
    vi = (vi > 0.f) ? vi : NEG_SLOPE * vi;
    float p = vi * ratt;
    #pragma unroll
    for (int off = 32; off > 0; off >>= 1) p += __shfl_xor(p, off, 64);
    float m = p, l = 1.f, acc = svi;

    for (int k = start; k < end; k += 4) {
        int n = end - k;
        int s0 = csr[k];
        int s1 = (n > 1) ? csr[k + 1] : s0;
        int s2 = (n > 2) ? csr[k + 2] : s0;
        int s3 = (n > 3) ? csr[k + 3] : s0;
        float sv0 = xl[(size_t)s0 * 64 + lane];
        float sv1 = xl[(size_t)s1 * 64 + lane];
        float sv2 = xl[(size_t)s2 * 64 + lane];
        float sv3 = xl[(size_t)s3 * 64 + lane];
        float v0 = sv0 + rxr; v0 = (v0 > 0.f) ? v0 : NEG_SLOPE * v0;
        float v1 = sv1 + rxr; v1 = (v1 > 0.f) ? v1 : NEG_SLOPE * v1;
        float v2 = sv2 + rxr; v2 = (v2 > 0.f) ? v2 : NEG_SLOPE * v2;
        float v3 = sv3 + rxr; v3 = (v3 > 0.f) ? v3 : NEG_SLOPE * v3;
        float p0 = v0 * ratt, p1 = v1 * ratt, p2 = v2 * ratt, p3 = v3 * ratt;
        #pragma unroll
        for (int off = 32; off > 0; off >>= 1) {
            p0 += __shfl_xor(p0, off, 64);
            p1 += __shfl_xor(p1, off, 64);
            p2 += __shfl_xor(p2, off, 64);
            p3 += __shfl_xor(p3, off, 64);
        }
        if (n < 2) p1 = -1e30f;
        if (n < 3) p2 = -1e30f;
        if (n < 4) p3 = -1e30f;
        float m4 = fmaxf(fmaxf(p0, p1), fmaxf(p2, p3));
        float e0 = __expf(p0 - m4);
        float e1 = __expf(p1 - m4);
        float e2 = __expf(p2 - m4);
        float e3 = __expf(p3 - m4);
        float l4 = (e0 + e1) + (e2 + e3);
        float a4 = fmaf(e0, sv0, e1 * sv1) + fmaf(e2, sv2, e3 * sv3);
        float nm = fmaxf(m, m4);
        float es = __expf(m - nm);
        float e4 = __expf(m4 - nm);
        l = fmaf(l, es, l4 * e4);
        acc = fmaf(acc, es, a4 * e4);
        m = nm;
    }
    out[(size_t)i * 64 + lane] = acc / l + bias[lane];
}

// ---------------------------------------------------------------------------

extern "C" void kernel_launch(void* const* d_in, const int* in_sizes, int n_in,
                              void* d_out, int out_size, void* d_ws, size_t ws_size,
                              hipStream_t stream) {
    const float* x    = (const float*)d_in[0];
    const void*  ei   = d_in[1];
    const float* Wl1  = (const float*)d_in[2];
    const float* Wr1  = (const float*)d_in[3];
    const float* att1 = (const float*)d_in[4];
    const float* b1   = (const float*)d_in[5];
    const float* Wl2  = (const float*)d_in[6];
    const float* Wr2  = (const float*)d_in[7];
    const float* att2 = (const float*)d_in[8];
    const float* b2   = (const float*)d_in[9];
    const float* Wl3  = (const float*)d_in[10];
    const float* Wr3  = (const float*)d_in[11];
    const float* att3 = (const float*)d_in[12];
    const float* b3   = (const float*)d_in[13];
    float* out = (float*)d_out;

    int N = in_sizes[0] / 256;
    int E = in_sizes[1] / 2;

    char* w = (char*)d_ws;
    float* xl = (float*)w; w += (size_t)N * 256 * sizeof(float);
    float* xr = (float*)w; w += (size_t)N * 256 * sizeof(float);
    float* h  = (float*)w; w += (size_t)N * 256 * sizeof(float);
    int* row_ptr = (int*)w; w += ((size_t)N + 2) * sizeof(int);
    int* deg     = (int*)w; w += (size_t)N * sizeof(int);
    int* csr     = (int*)w; w += (size_t)E * sizeof(int);
    int* flag    = (int*)w; w += 256;

    // --- CSR build (same graph for all 3 layers) ---
    detect_i64_kernel<<<1, 256, 0, stream>>>((const unsigned int*)ei, E, flag);
    fill_zero_kernel<<<(N + 255) / 256, 256, 0, stream>>>(deg, N);
    count_deg_kernel<<<(E + 255) / 256, 256, 0, stream>>>(ei, E, flag, deg);
    scan_kernel<<<1, 1024, 0, stream>>>(deg, row_ptr, N);
    fill_zero_kernel<<<(N + 255) / 256, 256, 0, stream>>>(deg, N);
    scatter_kernel<<<(E + 255) / 256, 256, 0, stream>>>(ei, E, flag, row_ptr, deg, csr);

    // --- Layer 1 ---
    dim3 g12((N + 63) / 64, 4);
    gemm_fused_kernel<<<g12, 256, 0, stream>>>(x, Wl1, Wr1, xl, xr, N, 256);
    agg_h8_kernel<<<N, 256, 0, stream>>>(xl, xr, att1, b1, row_ptr, csr, h, N, 1);

    // --- Layer 2 ---
    gemm_fused_kernel<<<g12, 256, 0, stream>>>(h, Wl2, Wr2, xl, xr, N, 256);
    agg_h8_kernel<<<N, 256, 0, stream>>>(xl, xr, att2, b2, row_ptr, csr, h, N, 1);

    // --- Layer 3 ---
    dim3 g3((N + 63) / 64, 1);
    gemm_fused_kernel<<<g3, 256, 0, stream>>>(h, Wl3, Wr3, xl, xr, N, 64);
    agg_h1_kernel<<<(N + 3) / 4, 256, 0, stream>>>(xl, xr, att3, b3, row_ptr, csr, out, N);
}

// Round 4
// 653.332 us; speedup vs baseline: 1.8336x; 1.3458x over previous
//
#include <hip/hip_runtime.h>

#define NEG_SLOPE 0.2f

typedef __attribute__((ext_vector_type(8))) short bf16x8;
typedef __attribute__((ext_vector_type(4))) float f32x4;

__device__ __forceinline__ unsigned short f2bf_rne(float x) {
    unsigned int u = __float_as_uint(x);
    unsigned int r = (u + 0x7FFFu + ((u >> 16) & 1u)) >> 16;
    return (unsigned short)r;
}

// ---------------------------------------------------------------------------
// CSR build
// ---------------------------------------------------------------------------

__global__ void fill_zero_kernel(int* __restrict__ p, int n) {
    int i = blockIdx.x * blockDim.x + threadIdx.x;
    if (i < n) p[i] = 0;
}

__global__ void detect_i64_kernel(const unsigned int* __restrict__ w, int E, int* __restrict__ flag) {
    __shared__ unsigned int ssum[256];
    int n = E < 4096 ? E : 4096;
    unsigned int local = 0;
    for (int k = threadIdx.x; k < n; k += 256) local |= w[2 * k + 1];
    ssum[threadIdx.x] = local;
    __syncthreads();
    for (int off = 128; off > 0; off >>= 1) {
        if (threadIdx.x < off) ssum[threadIdx.x] |= ssum[threadIdx.x + off];
        __syncthreads();
    }
    if (threadIdx.x == 0) flag[0] = (ssum[0] == 0) ? 1 : 0;
}

__global__ void count_deg_kernel(const void* __restrict__ eiv, int E,
                                 const int* __restrict__ flag, int* __restrict__ deg) {
    int e = blockIdx.x * blockDim.x + threadIdx.x;
    if (e >= E) return;
    int d;
    if (*flag) d = (int)((const long long*)eiv)[(size_t)E + e];
    else       d = ((const int*)eiv)[(size_t)E + e];
    atomicAdd(&deg[d], 1);
}

__global__ void scan_kernel(const int* __restrict__ deg, int* __restrict__ row_ptr, int N) {
    __shared__ int sd[1024];
    __shared__ int srun;
    int t = threadIdx.x;
    if (t == 0) { srun = 0; row_ptr[0] = 0; }
    __syncthreads();
    for (int base = 0; base < N; base += 1024) {
        int v = (base + t < N) ? deg[base + t] : 0;
        sd[t] = v;
        __syncthreads();
        for (int off = 1; off < 1024; off <<= 1) {
            int add = (t >= off) ? sd[t - off] : 0;
            __syncthreads();
            sd[t] += add;
            __syncthreads();
        }
        if (base + t < N) row_ptr[base + t + 1] = srun + sd[t];
        __syncthreads();
        if (t == 0) srun += sd[1023];
        __syncthreads();
    }
}

__global__ void scatter_kernel(const void* __restrict__ eiv, int E,
                               const int* __restrict__ flag,
                               const int* __restrict__ row_ptr,
                               int* __restrict__ cursor, int* __restrict__ csr) {
    int e = blockIdx.x * blockDim.x + threadIdx.x;
    if (e >= E) return;
    int s, d;
    if (*flag) {
        s = (int)((const long long*)eiv)[e];
        d = (int)((const long long*)eiv)[(size_t)E + e];
    } else {
        s = ((const int*)eiv)[e];
        d = ((const int*)eiv)[(size_t)E + e];
    }
    int pos = atomicAdd(&cursor[d], 1);
    csr[row_ptr[d] + pos] = s;
}

// ---------------------------------------------------------------------------
// fp32 -> bf16 hi/lo split (for node features x)
// ---------------------------------------------------------------------------

__global__ void split_kernel(const float* __restrict__ src, int n4,
                             unsigned short* __restrict__ hi, unsigned short* __restrict__ lo) {
    int i = blockIdx.x * blockDim.x + threadIdx.x;
    if (i >= n4) return;
    float4 v = *reinterpret_cast<const float4*>(&src[(size_t)i * 4]);
    ushort4 h, l;
    float f;
    h.x = f2bf_rne(v.x); f = v.x - __uint_as_float((unsigned int)h.x << 16); l.x = f2bf_rne(f);
    h.y = f2bf_rne(v.y); f = v.y - __uint_as_float((unsigned int)h.y << 16); l.y = f2bf_rne(f);
    h.z = f2bf_rne(v.z); f = v.z - __uint_as_float((unsigned int)h.z << 16); l.z = f2bf_rne(f);
    h.w = f2bf_rne(v.w); f = v.w - __uint_as_float((unsigned int)h.w << 16); l.w = f2bf_rne(f);
    *reinterpret_cast<ushort4*>(&hi[(size_t)i * 4]) = h;
    *reinterpret_cast<ushort4*>(&lo[(size_t)i * 4]) = l;
}

// Split + transpose weights: Wl,Wr [256][M] fp32 -> WT_hi/WT_lo [2M][256] bf16.
// blockIdx.x = k (0..255); threads cover m2.
__global__ void splitT_w_kernel(const float* __restrict__ Wl, const float* __restrict__ Wr, int M,
                                unsigned short* __restrict__ WThi, unsigned short* __restrict__ WTlo) {
    int k = blockIdx.x;
    int m2 = blockIdx.y * 256 + threadIdx.x;
    if (m2 >= 2 * M) return;
    float v = (m2 < M) ? Wl[(size_t)k * M + m2] : Wr[(size_t)k * M + (m2 - M)];
    unsigned short h = f2bf_rne(v);
    float fl = v - __uint_as_float((unsigned int)h << 16);
    WThi[(size_t)m2 * 256 + k] = h;
    WTlo[(size_t)m2 * 256 + k] = f2bf_rne(fl);
}

// ---------------------------------------------------------------------------
// MFMA GEMM: C[N][ldc] = A[N][256] @ WT^T, split-bf16 3-pass accumulation.
// A_hi/A_lo row-major [N][256] bf16; B = WT [ldc][256] bf16 (row = output col).
// Block: 256 thr = 4 waves (2x2), tile 128x128, BK=64, XOR-swizzled LDS.
// ---------------------------------------------------------------------------

__global__ __launch_bounds__(256) void gemm_mfma_kernel(
    const unsigned short* __restrict__ Ahi, const unsigned short* __restrict__ Alo,
    const unsigned short* __restrict__ Bhi, const unsigned short* __restrict__ Blo,
    float* __restrict__ C, int N, int ldc) {
    __shared__ unsigned short sA[2][128 * 64];
    __shared__ unsigned short sB[2][128 * 64];

    int t = threadIdx.x;
    int lane = t & 63;
    int w = t >> 6;
    int wr = (w >> 1) * 64;       // wave row offset in tile
    int wc = (w & 1) * 64;        // wave col offset in tile
    int row0 = blockIdx.x * 128;
    int n0 = blockIdx.y * 128;

    int l15 = lane & 15;
    int l4 = lane >> 4;

    f32x4 acc[4][4] = {};

    // staging map: iteration i covers chunk c = i*256+t; row=c>>3, kc=c&7
    int skc = t & 7;

    for (int k0 = 0; k0 < 256; k0 += 64) {
        __syncthreads();
        #pragma unroll
        for (int i = 0; i < 4; ++i) {
            int row = i * 32 + (t >> 3);
            int dst = row * 64 + ((skc * 8) ^ ((row & 7) << 3));
            int ar = row0 + row; if (ar >= N) ar = N - 1;
            uint4 vh = *reinterpret_cast<const uint4*>(&Ahi[(size_t)ar * 256 + k0 + skc * 8]);
            uint4 vl = *reinterpret_cast<const uint4*>(&Alo[(size_t)ar * 256 + k0 + skc * 8]);
            *reinterpret_cast<uint4*>(&sA[0][dst]) = vh;
            *reinterpret_cast<uint4*>(&sA[1][dst]) = vl;
            int bc = n0 + row;  // output-col row of WT; always in range (ldc multiple of 128)
            uint4 wh = *reinterpret_cast<const uint4*>(&Bhi[(size_t)bc * 256 + k0 + skc * 8]);
            uint4 wl = *reinterpret_cast<const uint4*>(&Blo[(size_t)bc * 256 + k0 + skc * 8]);
            *reinterpret_cast<uint4*>(&sB[0][dst]) = wh;
            *reinterpret_cast<uint4*>(&sB[1][dst]) = wl;
        }
        __syncthreads();

        #pragma unroll
        for (int ksub = 0; ksub < 2; ++ksub) {
            int kb = ksub * 32 + l4 * 8;   // ushort offset within row
            bf16x8 bh[4], bl[4];
            #pragma unroll
            for (int fc = 0; fc < 4; ++fc) {
                int c = wc + fc * 16 + l15;
                int idx = c * 64 + (kb ^ ((c & 7) << 3));
                bh[fc] = *reinterpret_cast<const bf16x8*>(&sB[0][idx]);
                bl[fc] = *reinterpret_cast<const bf16x8*>(&sB[1][idx]);
            }
            #pragma unroll
            for (int fr = 0; fr < 4; ++fr) {
                int r = wr + fr * 16 + l15;
                int idx = r * 64 + (kb ^ ((r & 7) << 3));
                bf16x8 ah = *reinterpret_cast<const bf16x8*>(&sA[0][idx]);
                bf16x8 al = *reinterpret_cast<const bf16x8*>(&sA[1][idx]);
                #pragma unroll
                for (int fc = 0; fc < 4; ++fc) {
                    acc[fr][fc] = __builtin_amdgcn_mfma_f32_16x16x32_bf16(ah, bh[fc], acc[fr][fc], 0, 0, 0);
                    acc[fr][fc] = __builtin_amdgcn_mfma_f32_16x16x32_bf16(ah, bl[fc], acc[fr][fc], 0, 0, 0);
                    acc[fr][fc] = __builtin_amdgcn_mfma_f32_16x16x32_bf16(al, bh[fc], acc[fr][fc], 0, 0, 0);
                }
            }
        }
    }

    // C write: col = n0+wc+fc*16+l15 ; row = row0+wr+fr*16+l4*4+j
    #pragma unroll
    for (int fr = 0; fr < 4; ++fr) {
        #pragma unroll
        for (int j = 0; j < 4; ++j) {
            int row = row0 + wr + fr * 16 + l4 * 4 + j;
            if (row < N) {
                #pragma unroll
                for (int fc = 0; fc < 4; ++fc) {
                    int col = n0 + wc + fc * 16 + l15;
                    C[(size_t)row * ldc + col] = acc[fr][fc][j];
                }
            }
        }
    }
}

// ---------------------------------------------------------------------------
// agg_h8: one block (4 waves) per node, lane owns a float4 of channels.
// Reads xl/xr from C[N][ld] (xl at col 0, xr at col ld/2). Output: bf16 hi/lo.
// ---------------------------------------------------------------------------

__device__ __forceinline__ float lrelu_dot4(const float4 sv, const float4 rxr, const float4 a) {
    float v0 = sv.x + rxr.x; v0 = (v0 > 0.f) ? v0 : NEG_SLOPE * v0;
    float v1 = sv.y + rxr.y; v1 = (v1 > 0.f) ? v1 : NEG_SLOPE * v1;
    float v2 = sv.z + rxr.z; v2 = (v2 > 0.f) ? v2 : NEG_SLOPE * v2;
    float v3 = sv.w + rxr.w; v3 = (v3 > 0.f) ? v3 : NEG_SLOPE * v3;
    return fmaf(v0, a.x, fmaf(v1, a.y, fmaf(v2, a.z, v3 * a.w)));
}

__global__ __launch_bounds__(256) void agg_h8_kernel(
    const float* __restrict__ Cin, int ld,
    const float* __restrict__ att, const float* __restrict__ bias,
    const int* __restrict__ row_ptr, const int* __restrict__ csr,
    unsigned short* __restrict__ ohi, unsigned short* __restrict__ olo, int N) {
    int i = blockIdx.x;
    int t = threadIdx.x;
    int w = t >> 6;
    int lam = t & 63;
    int o = lam * 4;
    int h = lam >> 3;

    const float* xl = Cin;
    const float* xr = Cin + 256;

    const float4 rxr = *reinterpret_cast<const float4*>(&xr[(size_t)i * ld + o]);
    const float4 at4 = *reinterpret_cast<const float4*>(&att[o]);
    int start = row_ptr[i], end = row_ptr[i + 1];

    float m, l;
    float4 acc;
    if (w == 0) {
        float4 svi = *reinterpret_cast<const float4*>(&xl[(size_t)i * ld + o]);
        float p = lrelu_dot4(svi, rxr, at4);
        #pragma unroll
        for (int off = 4; off > 0; off >>= 1) p += __shfl_xor(p, off, 8);
        m = p; l = 1.f; acc = svi;
    } else {
        m = -1e30f; l = 0.f; acc = make_float4(0.f, 0.f, 0.f, 0.f);
    }

    for (int k = start + w; k < end; k += 16) {
        int s0 = csr[k];
        int s1 = (k + 4  < end) ? csr[k + 4]  : s0;
        int s2 = (k + 8  < end) ? csr[k + 8]  : s0;
        int s3 = (k + 12 < end) ? csr[k + 12] : s0;
        float4 sv0 = *reinterpret_cast<const float4*>(&xl[(size_t)s0 * ld + o]);
        float4 sv1 = *reinterpret_cast<const float4*>(&xl[(size_t)s1 * ld + o]);
        float4 sv2 = *reinterpret_cast<const float4*>(&xl[(size_t)s2 * ld + o]);
        float4 sv3 = *reinterpret_cast<const float4*>(&xl[(size_t)s3 * ld + o]);
        float p0 = lrelu_dot4(sv0, rxr, at4);
        float p1 = lrelu_dot4(sv1, rxr, at4);
        float p2 = lrelu_dot4(sv2, rxr, at4);
        float p3 = lrelu_dot4(sv3, rxr, at4);
        #pragma unroll
        for (int off = 4; off > 0; off >>= 1) {
            p0 += __shfl_xor(p0, off, 8);
            p1 += __shfl_xor(p1, off, 8);
            p2 += __shfl_xor(p2, off, 8);
            p3 += __shfl_xor(p3, off, 8);
        }
        if (k + 4  >= end) p1 = -1e30f;
        if (k + 8  >= end) p2 = -1e30f;
        if (k + 12 >= end) p3 = -1e30f;
        float m4 = fmaxf(fmaxf(p0, p1), fmaxf(p2, p3));
        float e0 = __expf(p0 - m4);
        float e1 = __expf(p1 - m4);
        float e2 = __expf(p2 - m4);
        float e3 = __expf(p3 - m4);
        float l4 = (e0 + e1) + (e2 + e3);
        float nm = fmaxf(m, m4);
        float es = __expf(m - nm);
        float e4 = __expf(m4 - nm);
        l = fmaf(l, es, l4 * e4);
        acc.x = fmaf(acc.x, es, (fmaf(e0, sv0.x, e1 * sv1.x) + fmaf(e2, sv2.x, e3 * sv3.x)) * e4);
        acc.y = fmaf(acc.y, es, (fmaf(e0, sv0.y, e1 * sv1.y) + fmaf(e2, sv2.y, e3 * sv3.y)) * e4);
        acc.z = fmaf(acc.z, es, (fmaf(e0, sv0.z, e1 * sv1.z) + fmaf(e2, sv2.z, e3 * sv3.z)) * e4);
        acc.w = fmaf(acc.w, es, (fmaf(e0, sv0.w, e1 * sv1.w) + fmaf(e2, sv2.w, e3 * sv3.w)) * e4);
        m = nm;
    }

    __shared__ float sm[4][8];
    __shared__ float sl[4][8];
    __shared__ float sacc[4][256];
    if ((lam & 7) == 0) { sm[w][h] = m; sl[w][h] = l; }
    *reinterpret_cast<float4*>(&sacc[w][o]) = acc;
    __syncthreads();

    int hh = t >> 5;
    float M = fmaxf(fmaxf(sm[0][hh], sm[1][hh]), fmaxf(sm[2][hh], sm[3][hh]));
    float ew0 = __expf(sm[0][hh] - M);
    float ew1 = __expf(sm[1][hh] - M);
    float ew2 = __expf(sm[2][hh] - M);
    float ew3 = __expf(sm[3][hh] - M);
    float den = fmaf(ew0, sl[0][hh], ew1 * sl[1][hh]) + fmaf(ew2, sl[2][hh], ew3 * sl[3][hh]);
    float num = fmaf(ew0, sacc[0][t], ew1 * sacc[1][t]) + fmaf(ew2, sacc[2][t], ew3 * sacc[3][t]);
    float res = num / den + bias[t];
    res = (res > 0.f) ? res : (__expf(res) - 1.0f);  // ELU (layers 1-2 only)
    unsigned short hb = f2bf_rne(res);
    float fl = res - __uint_as_float((unsigned int)hb << 16);
    ohi[(size_t)i * 256 + t] = hb;
    olo[(size_t)i * 256 + t] = f2bf_rne(fl);
}

// Layer 3: H=1, C=64. One wave per node; 4 nodes per block. C stride 128.
__global__ __launch_bounds__(256) void agg_h1_kernel(
    const float* __restrict__ Cin,
    const float* __restrict__ att, const float* __restrict__ bias,
    const int* __restrict__ row_ptr, const int* __restrict__ csr,
    float* __restrict__ out, int N) {
    int lane = threadIdx.x & 63;
    int wv = threadIdx.x >> 6;
    int i = blockIdx.x * 4 + wv;
    if (i >= N) return;
    const float* xl = Cin;
    const float* xr = Cin + 64;
    float rxr = xr[(size_t)i * 128 + lane];
    float ratt = att[lane];
    int start = row_ptr[i], end = row_ptr[i + 1];

    float svi = xl[(size_t)i * 128 + lane];
    float vi = svi + rxr;
    vi = (vi > 0.f) ? vi : NEG_SLOPE * vi;
    float p = vi * ratt;
    #pragma unroll
    for (int off = 32; off > 0; off >>= 1) p += __shfl_xor(p, off, 64);
    float m = p, l = 1.f, acc = svi;

    for (int k = start; k < end; k += 4) {
        int n = end - k;
        int s0 = csr[k];
        int s1 = (n > 1) ? csr[k + 1] : s0;
        int s2 = (n > 2) ? csr[k + 2] : s0;
        int s3 = (n > 3) ? csr[k + 3] : s0;
        float sv0 = xl[(size_t)s0 * 128 + lane];
        float sv1 = xl[(size_t)s1 * 128 + lane];
        float sv2 = xl[(size_t)s2 * 128 + lane];
        float sv3 = xl[(size_t)s3 * 128 + lane];
        float v0 = sv0 + rxr; v0 = (v0 > 0.f) ? v0 : NEG_SLOPE * v0;
        float v1 = sv1 + rxr; v1 = (v1 > 0.f) ? v1 : NEG_SLOPE * v1;
        float v2 = sv2 + rxr; v2 = (v2 > 0.f) ? v2 : NEG_SLOPE * v2;
        float v3 = sv3 + rxr; v3 = (v3 > 0.f) ? v3 : NEG_SLOPE * v3;
        float p0 = v0 * ratt, p1 = v1 * ratt, p2 = v2 * ratt, p3 = v3 * ratt;
        #pragma unroll
        for (int off = 32; off > 0; off >>= 1) {
            p0 += __shfl_xor(p0, off, 64);
            p1 += __shfl_xor(p1, off, 64);
            p2 += __shfl_xor(p2, off, 64);
            p3 += __shfl_xor(p3, off, 64);
        }
        if (n < 2) p1 = -1e30f;
        if (n < 3) p2 = -1e30f;
        if (n < 4) p3 = -1e30f;
        float m4 = fmaxf(fmaxf(p0, p1), fmaxf(p2, p3));
        float e0 = __expf(p0 - m4);
        float e1 = __expf(p1 - m4);
        float e2 = __expf(p2 - m4);
        float e3 = __expf(p3 - m4);
        float l4 = (e0 + e1) + (e2 + e3);
        float a4 = fmaf(e0, sv0, e1 * sv1) + fmaf(e2, sv2, e3 * sv3);
        float nm = fmaxf(m, m4);
        float es = __expf(m - nm);
        float e4 = __expf(m4 - nm);
        l = fmaf(l, es, l4 * e4);
        acc = fmaf(acc, es, a4 * e4);
        m = nm;
    }
    out[(size_t)i * 64 + lane] = acc / l + bias[lane];
}

// ---------------------------------------------------------------------------

extern "C" void kernel_launch(void* const* d_in, const int* in_sizes, int n_in,
                              void* d_out, int out_size, void* d_ws, size_t ws_size,
                              hipStream_t stream) {
    const float* x    = (const float*)d_in[0];
    const void*  ei   = d_in[1];
    const float* Wl1  = (const float*)d_in[2];
    const float* Wr1  = (const float*)d_in[3];
    const float* att1 = (const float*)d_in[4];
    const float* b1   = (const float*)d_in[5];
    const float* Wl2  = (const float*)d_in[6];
    const float* Wr2  = (const float*)d_in[7];
    const float* att2 = (const float*)d_in[8];
    const float* b2   = (const float*)d_in[9];
    const float* Wl3  = (const float*)d_in[10];
    const float* Wr3  = (const float*)d_in[11];
    const float* att3 = (const float*)d_in[12];
    const float* b3   = (const float*)d_in[13];
    float* out = (float*)d_out;

    int N = in_sizes[0] / 256;
    int E = in_sizes[1] / 2;

    char* w = (char*)d_ws;
    unsigned short* h_hi = (unsigned short*)w; w += (size_t)N * 256 * 2;
    unsigned short* h_lo = (unsigned short*)w; w += (size_t)N * 256 * 2;
    float* C = (float*)w;          w += (size_t)N * 512 * sizeof(float);
    unsigned short* WT_hi = (unsigned short*)w; w += (size_t)512 * 256 * 2;
    unsigned short* WT_lo = (unsigned short*)w; w += (size_t)512 * 256 * 2;
    int* row_ptr = (int*)w; w += ((size_t)N + 2) * sizeof(int);
    int* deg     = (int*)w; w += (size_t)N * sizeof(int);
    int* csr     = (int*)w; w += (size_t)E * sizeof(int);
    int* flag    = (int*)w; w += 256;

    // --- CSR build ---
    detect_i64_kernel<<<1, 256, 0, stream>>>((const unsigned int*)ei, E, flag);
    fill_zero_kernel<<<(N + 255) / 256, 256, 0, stream>>>(deg, N);
    count_deg_kernel<<<(E + 255) / 256, 256, 0, stream>>>(ei, E, flag, deg);
    scan_kernel<<<1, 1024, 0, stream>>>(deg, row_ptr, N);
    fill_zero_kernel<<<(N + 255) / 256, 256, 0, stream>>>(deg, N);
    scatter_kernel<<<(E + 255) / 256, 256, 0, stream>>>(ei, E, flag, row_ptr, deg, csr);

    int gemm_gx = (N + 127) / 128;

    // --- Layer 1 ---
    split_kernel<<<((N * 256 / 4) + 255) / 256, 256, 0, stream>>>(x, N * 256 / 4, h_hi, h_lo);
    splitT_w_kernel<<<dim3(256, 2), 256, 0, stream>>>(Wl1, Wr1, 256, WT_hi, WT_lo);
    gemm_mfma_kernel<<<dim3(gemm_gx, 4), 256, 0, stream>>>(h_hi, h_lo, WT_hi, WT_lo, C, N, 512);
    agg_h8_kernel<<<N, 256, 0, stream>>>(C, 512, att1, b1, row_ptr, csr, h_hi, h_lo, N);

    // --- Layer 2 ---
    splitT_w_kernel<<<dim3(256, 2), 256, 0, stream>>>(Wl2, Wr2, 256, WT_hi, WT_lo);
    gemm_mfma_kernel<<<dim3(gemm_gx, 4), 256, 0, stream>>>(h_hi, h_lo, WT_hi, WT_lo, C, N, 512);
    agg_h8_kernel<<<N, 256, 0, stream>>>(C, 512, att2, b2, row_ptr, csr, h_hi, h_lo, N);

    // --- Layer 3 ---
    splitT_w_kernel<<<dim3(256, 1), 256, 0, stream>>>(Wl3, Wr3, 64, WT_hi, WT_lo);
    gemm_mfma_kernel<<<dim3(gemm_gx, 1), 256, 0, stream>>>(h_hi, h_lo, WT_hi, WT_lo, C, N, 128);
    agg_h1_kernel<<<(N + 3) / 4, 256, 0, stream>>>(C, att3, b3, row_ptr, csr, out, N);
}

// Round 5
// 562.390 us; speedup vs baseline: 2.1301x; 1.1617x over previous
//
#include <hip/hip_runtime.h>

#define NEG_SLOPE 0.2f

typedef __attribute__((ext_vector_type(8))) short bf16x8;
typedef __attribute__((ext_vector_type(4))) float f32x4;

__device__ __forceinline__ unsigned short f2bf_rne(float x) {
    unsigned int u = __float_as_uint(x);
    unsigned int r = (u + 0x7FFFu + ((u >> 16) & 1u)) >> 16;
    return (unsigned short)r;
}

// ---------------------------------------------------------------------------
// CSR build
// ---------------------------------------------------------------------------

__global__ void fill_zero_kernel(int* __restrict__ p, int n) {
    int i = blockIdx.x * blockDim.x + threadIdx.x;
    if (i < n) p[i] = 0;
}

__global__ void detect_i64_kernel(const unsigned int* __restrict__ w, int E, int* __restrict__ flag) {
    __shared__ unsigned int ssum[256];
    int n = E < 4096 ? E : 4096;
    unsigned int local = 0;
    for (int k = threadIdx.x; k < n; k += 256) local |= w[2 * k + 1];
    ssum[threadIdx.x] = local;
    __syncthreads();
    for (int off = 128; off > 0; off >>= 1) {
        if (threadIdx.x < off) ssum[threadIdx.x] |= ssum[threadIdx.x + off];
        __syncthreads();
    }
    if (threadIdx.x == 0) flag[0] = (ssum[0] == 0) ? 1 : 0;
}

__global__ void count_deg_kernel(const void* __restrict__ eiv, int E,
                                 const int* __restrict__ flag, int* __restrict__ deg) {
    int e = blockIdx.x * blockDim.x + threadIdx.x;
    if (e >= E) return;
    int d;
    if (*flag) d = (int)((const long long*)eiv)[(size_t)E + e];
    else       d = ((const int*)eiv)[(size_t)E + e];
    atomicAdd(&deg[d], 1);
}

// 3-kernel scan: per-block inclusive scan, top scan, add offsets.
__global__ void scan_block_kernel(const int* __restrict__ deg, int* __restrict__ row_ptr,
                                  int* __restrict__ partial, int N) {
    __shared__ int sd[1024];
    int t = threadIdx.x;
    int g = blockIdx.x * 1024 + t;
    int v = (g < N) ? deg[g] : 0;
    sd[t] = v;
    __syncthreads();
    for (int off = 1; off < 1024; off <<= 1) {
        int add = (t >= off) ? sd[t - off] : 0;
        __syncthreads();
        sd[t] += add;
        __syncthreads();
    }
    if (g < N) row_ptr[g + 1] = sd[t];
    if (t == 1023) partial[blockIdx.x] = sd[1023];
    if (g == 0) row_ptr[0] = 0;
}

__global__ void scan_top_kernel(int* __restrict__ partial, int nb) {
    if (threadIdx.x == 0 && blockIdx.x == 0) {
        int run = 0;
        for (int j = 0; j < nb; ++j) { run += partial[j]; partial[j] = run; }
    }
}

__global__ void scan_addoff_kernel(int* __restrict__ row_ptr, const int* __restrict__ partial, int N) {
    int g = blockIdx.x * 256 + threadIdx.x;
    if (g >= N) return;
    int b = g >> 10;
    if (b > 0) row_ptr[g + 1] += partial[b - 1];
}

__global__ void scatter_kernel(const void* __restrict__ eiv, int E,
                               const int* __restrict__ flag,
                               const int* __restrict__ row_ptr,
                               int* __restrict__ cursor, int* __restrict__ csr) {
    int e = blockIdx.x * blockDim.x + threadIdx.x;
    if (e >= E) return;
    int s, d;
    if (*flag) {
        s = (int)((const long long*)eiv)[e];
        d = (int)((const long long*)eiv)[(size_t)E + e];
    } else {
        s = ((const int*)eiv)[e];
        d = ((const int*)eiv)[(size_t)E + e];
    }
    int pos = atomicAdd(&cursor[d], 1);
    csr[row_ptr[d] + pos] = s;
}

// ---------------------------------------------------------------------------
// fp32 -> bf16 hi/lo split
// ---------------------------------------------------------------------------

__global__ void split_kernel(const float* __restrict__ src, int n4,
                             unsigned short* __restrict__ hi, unsigned short* __restrict__ lo) {
    int i = blockIdx.x * blockDim.x + threadIdx.x;
    if (i >= n4) return;
    float4 v = *reinterpret_cast<const float4*>(&src[(size_t)i * 4]);
    ushort4 h, l;
    float f;
    h.x = f2bf_rne(v.x); f = v.x - __uint_as_float((unsigned int)h.x << 16); l.x = f2bf_rne(f);
    h.y = f2bf_rne(v.y); f = v.y - __uint_as_float((unsigned int)h.y << 16); l.y = f2bf_rne(f);
    h.z = f2bf_rne(v.z); f = v.z - __uint_as_float((unsigned int)h.z << 16); l.z = f2bf_rne(f);
    h.w = f2bf_rne(v.w); f = v.w - __uint_as_float((unsigned int)h.w << 16); l.w = f2bf_rne(f);
    *reinterpret_cast<ushort4*>(&hi[(size_t)i * 4]) = h;
    *reinterpret_cast<ushort4*>(&lo[(size_t)i * 4]) = l;
}

__global__ void splitT_w_kernel(const float* __restrict__ Wl, const float* __restrict__ Wr, int M,
                                unsigned short* __restrict__ WThi, unsigned short* __restrict__ WTlo) {
    int k = blockIdx.x;
    int m2 = blockIdx.y * 256 + threadIdx.x;
    if (m2 >= 2 * M) return;
    float v = (m2 < M) ? Wl[(size_t)k * M + m2] : Wr[(size_t)k * M + (m2 - M)];
    unsigned short h = f2bf_rne(v);
    float fl = v - __uint_as_float((unsigned int)h << 16);
    WThi[(size_t)m2 * 256 + k] = h;
    WTlo[(size_t)m2 * 256 + k] = f2bf_rne(fl);
}

// ---------------------------------------------------------------------------
// MFMA GEMM (split-bf16, 3 passes), tile 128x128, BK=64, XOR-swizzled LDS.
// ---------------------------------------------------------------------------

__global__ __launch_bounds__(256) void gemm_mfma_kernel(
    const unsigned short* __restrict__ Ahi, const unsigned short* __restrict__ Alo,
    const unsigned short* __restrict__ Bhi, const unsigned short* __restrict__ Blo,
    float* __restrict__ C, int N, int ldc) {
    __shared__ unsigned short sA[2][128 * 64];
    __shared__ unsigned short sB[2][128 * 64];

    int t = threadIdx.x;
    int lane = t & 63;
    int w = t >> 6;
    int wr = (w >> 1) * 64;
    int wc = (w & 1) * 64;
    int row0 = blockIdx.x * 128;
    int n0 = blockIdx.y * 128;

    int l15 = lane & 15;
    int l4 = lane >> 4;

    f32x4 acc[4][4] = {};

    int skc = t & 7;

    for (int k0 = 0; k0 < 256; k0 += 64) {
        __syncthreads();
        #pragma unroll
        for (int i = 0; i < 4; ++i) {
            int row = i * 32 + (t >> 3);
            int dst = row * 64 + ((skc * 8) ^ ((row & 7) << 3));
            int ar = row0 + row; if (ar >= N) ar = N - 1;
            uint4 vh = *reinterpret_cast<const uint4*>(&Ahi[(size_t)ar * 256 + k0 + skc * 8]);
            uint4 vl = *reinterpret_cast<const uint4*>(&Alo[(size_t)ar * 256 + k0 + skc * 8]);
            *reinterpret_cast<uint4*>(&sA[0][dst]) = vh;
            *reinterpret_cast<uint4*>(&sA[1][dst]) = vl;
            int bc = n0 + row;
            uint4 wh = *reinterpret_cast<const uint4*>(&Bhi[(size_t)bc * 256 + k0 + skc * 8]);
            uint4 wl = *reinterpret_cast<const uint4*>(&Blo[(size_t)bc * 256 + k0 + skc * 8]);
            *reinterpret_cast<uint4*>(&sB[0][dst]) = wh;
            *reinterpret_cast<uint4*>(&sB[1][dst]) = wl;
        }
        __syncthreads();

        #pragma unroll
        for (int ksub = 0; ksub < 2; ++ksub) {
            int kb = ksub * 32 + l4 * 8;
            bf16x8 bh[4], bl[4];
            #pragma unroll
            for (int fc = 0; fc < 4; ++fc) {
                int c = wc + fc * 16 + l15;
                int idx = c * 64 + (kb ^ ((c & 7) << 3));
                bh[fc] = *reinterpret_cast<const bf16x8*>(&sB[0][idx]);
                bl[fc] = *reinterpret_cast<const bf16x8*>(&sB[1][idx]);
            }
            #pragma unroll
            for (int fr = 0; fr < 4; ++fr) {
                int r = wr + fr * 16 + l15;
                int idx = r * 64 + (kb ^ ((r & 7) << 3));
                bf16x8 ah = *reinterpret_cast<const bf16x8*>(&sA[0][idx]);
                bf16x8 al = *reinterpret_cast<const bf16x8*>(&sA[1][idx]);
                #pragma unroll
                for (int fc = 0; fc < 4; ++fc) {
                    acc[fr][fc] = __builtin_amdgcn_mfma_f32_16x16x32_bf16(ah, bh[fc], acc[fr][fc], 0, 0, 0);
                    acc[fr][fc] = __builtin_amdgcn_mfma_f32_16x16x32_bf16(ah, bl[fc], acc[fr][fc], 0, 0, 0);
                    acc[fr][fc] = __builtin_amdgcn_mfma_f32_16x16x32_bf16(al, bh[fc], acc[fr][fc], 0, 0, 0);
                }
            }
        }
    }

    #pragma unroll
    for (int fr = 0; fr < 4; ++fr) {
        #pragma unroll
        for (int j = 0; j < 4; ++j) {
            int row = row0 + wr + fr * 16 + l4 * 4 + j;
            if (row < N) {
                #pragma unroll
                for (int fc = 0; fc < 4; ++fc) {
                    int col = n0 + wc + fc * 16 + l15;
                    C[(size_t)row * ldc + col] = acc[fr][fc][j];
                }
            }
        }
    }
}

// ---------------------------------------------------------------------------
// agg_h8 v4: ONE WAVE per node. Lane layout: half = lane>>5 selects which of 2
// parallel edges; lq = lane&31 owns channels [lq*8, lq*8+8). Head = 32ch = 4
// lanes -> 2-level shuffle reduce. Fixed-m online softmax (m = self-logit,
// never updated; exponent clamped), so no rescale chain. Halves merged by one
// xor-32 shuffle pass. Block = 4 waves = 4 nodes, no __syncthreads.
// ---------------------------------------------------------------------------

__global__ __launch_bounds__(256) void agg_h8_kernel(
    const float* __restrict__ Cin, int ld,
    const float* __restrict__ att, const float* __restrict__ bias,
    const int* __restrict__ row_ptr, const int* __restrict__ csr,
    unsigned short* __restrict__ ohi, unsigned short* __restrict__ olo, int N) {
    int wv = threadIdx.x >> 6;
    int i = blockIdx.x * 4 + wv;
    if (i >= N) return;
    int lane = threadIdx.x & 63;
    int half = lane >> 5;
    int cb = (lane & 31) * 8;
    const float* xl = Cin;
    const float* xr = Cin + (ld >> 1);

    float rxr[8], a6[8], a4[8];
    {
        float4 r0 = *reinterpret_cast<const float4*>(&xr[(size_t)i * ld + cb]);
        float4 r1 = *reinterpret_cast<const float4*>(&xr[(size_t)i * ld + cb + 4]);
        rxr[0] = r0.x; rxr[1] = r0.y; rxr[2] = r0.z; rxr[3] = r0.w;
        rxr[4] = r1.x; rxr[5] = r1.y; rxr[6] = r1.z; rxr[7] = r1.w;
        float4 w0 = *reinterpret_cast<const float4*>(&att[cb]);
        float4 w1 = *reinterpret_cast<const float4*>(&att[cb + 4]);
        float aa[8] = {w0.x, w0.y, w0.z, w0.w, w1.x, w1.y, w1.z, w1.w};
        #pragma unroll
        for (int c = 0; c < 8; ++c) { a6[c] = 0.6f * aa[c]; a4[c] = 0.4f * aa[c]; }
    }

    float acc[8], l, m;
    {
        // self-loop: logit computed identically by both halves (same data, same ops)
        float4 u0 = *reinterpret_cast<const float4*>(&xl[(size_t)i * ld + cb]);
        float4 u1 = *reinterpret_cast<const float4*>(&xl[(size_t)i * ld + cb + 4]);
        float u[8] = {u0.x, u0.y, u0.z, u0.w, u1.x, u1.y, u1.z, u1.w};
        float p = 0.f;
        #pragma unroll
        for (int c = 0; c < 8; ++c) {
            float v = u[c] + rxr[c];
            p = fmaf(a6[c], v, p);
            p = fmaf(a4[c], fabsf(v), p);
        }
        p += __shfl_xor(p, 1, 4);
        p += __shfl_xor(p, 2, 4);
        m = p;
        l = half ? 0.f : 1.f;
        #pragma unroll
        for (int c = 0; c < 8; ++c) acc[c] = half ? 0.f : u[c];
    }

    int start = row_ptr[i], end = row_ptr[i + 1];
    for (int k = start; k < end; k += 4) {
        int kk0 = k + half;
        int kk1 = k + 2 + half;
        int s0 = (kk0 < end) ? csr[kk0] : i;
        int s1 = (kk1 < end) ? csr[kk1] : i;
        float4 a0 = *reinterpret_cast<const float4*>(&xl[(size_t)s0 * ld + cb]);
        float4 a1 = *reinterpret_cast<const float4*>(&xl[(size_t)s0 * ld + cb + 4]);
        float4 b0 = *reinterpret_cast<const float4*>(&xl[(size_t)s1 * ld + cb]);
        float4 b1 = *reinterpret_cast<const float4*>(&xl[(size_t)s1 * ld + cb + 4]);
        float ua[8] = {a0.x, a0.y, a0.z, a0.w, a1.x, a1.y, a1.z, a1.w};
        float ub[8] = {b0.x, b0.y, b0.z, b0.w, b1.x, b1.y, b1.z, b1.w};
        float p0 = 0.f, p1 = 0.f;
        #pragma unroll
        for (int c = 0; c < 8; ++c) {
            float v0 = ua[c] + rxr[c];
            p0 = fmaf(a6[c], v0, p0);
            p0 = fmaf(a4[c], fabsf(v0), p0);
            float v1 = ub[c] + rxr[c];
            p1 = fmaf(a6[c], v1, p1);
            p1 = fmaf(a4[c], fabsf(v1), p1);
        }
        p0 += __shfl_xor(p0, 1, 4);
        p0 += __shfl_xor(p0, 2, 4);
        p1 += __shfl_xor(p1, 1, 4);
        p1 += __shfl_xor(p1, 2, 4);
        float e0 = (kk0 < end) ? __expf(fminf(p0 - m, 60.f)) : 0.f;
        float e1 = (kk1 < end) ? __expf(fminf(p1 - m, 60.f)) : 0.f;
        l += e0 + e1;
        #pragma unroll
        for (int c = 0; c < 8; ++c) acc[c] = fmaf(e0, ua[c], fmaf(e1, ub[c], acc[c]));
    }

    // merge the two halves
    l += __shfl_xor(l, 32, 64);
    #pragma unroll
    for (int c = 0; c < 8; ++c) acc[c] += __shfl_xor(acc[c], 32, 64);

    if (half == 0) {
        float4 bb0 = *reinterpret_cast<const float4*>(&bias[cb]);
        float4 bb1 = *reinterpret_cast<const float4*>(&bias[cb + 4]);
        float bs[8] = {bb0.x, bb0.y, bb0.z, bb0.w, bb1.x, bb1.y, bb1.z, bb1.w};
        float inv = 1.0f / l;
        unsigned int hw[4], lw[4];
        #pragma unroll
        for (int c2 = 0; c2 < 4; ++c2) {
            float r0 = fmaf(acc[2 * c2], inv, bs[2 * c2]);
            float r1 = fmaf(acc[2 * c2 + 1], inv, bs[2 * c2 + 1]);
            r0 = (r0 > 0.f) ? r0 : (__expf(r0) - 1.f);   // ELU (layers 1-2)
            r1 = (r1 > 0.f) ? r1 : (__expf(r1) - 1.f);
            unsigned short h0 = f2bf_rne(r0), h1 = f2bf_rne(r1);
            float f0 = r0 - __uint_as_float((unsigned int)h0 << 16);
            float f1 = r1 - __uint_as_float((unsigned int)h1 << 16);
            unsigned short l0 = f2bf_rne(f0), l1 = f2bf_rne(f1);
            hw[c2] = (unsigned int)h0 | ((unsigned int)h1 << 16);
            lw[c2] = (unsigned int)l0 | ((unsigned int)l1 << 16);
        }
        *reinterpret_cast<uint4*>(&ohi[(size_t)i * 256 + cb]) = make_uint4(hw[0], hw[1], hw[2], hw[3]);
        *reinterpret_cast<uint4*>(&olo[(size_t)i * 256 + cb]) = make_uint4(lw[0], lw[1], lw[2], lw[3]);
    }
}

// ---------------------------------------------------------------------------
// agg_h1 v4 (layer 3): C=64, H=1. One wave per node: 8 edge-slots x 8 lanes x
// 8 channels. Fixed-m softmax, 3-level reduce within 8 lanes, 3-level merge.
// ---------------------------------------------------------------------------

__global__ __launch_bounds__(256) void agg_h1_kernel(
    const float* __restrict__ Cin,
    const float* __restrict__ att, const float* __restrict__ bias,
    const int* __restrict__ row_ptr, const int* __restrict__ csr,
    float* __restrict__ out, int N) {
    int wv = threadIdx.x >> 6;
    int i = blockIdx.x * 4 + wv;
    if (i >= N) return;
    int lane = threadIdx.x & 63;
    int es = lane >> 3;
    int cb = (lane & 7) * 8;
    const float* xl = Cin;
    const float* xr = Cin + 64;

    float rxr[8], a6[8], a4[8];
    {
        float4 r0 = *reinterpret_cast<const float4*>(&xr[(size_t)i * 128 + cb]);
        float4 r1 = *reinterpret_cast<const float4*>(&xr[(size_t)i * 128 + cb + 4]);
        rxr[0] = r0.x; rxr[1] = r0.y; rxr[2] = r0.z; rxr[3] = r0.w;
        rxr[4] = r1.x; rxr[5] = r1.y; rxr[6] = r1.z; rxr[7] = r1.w;
        float4 w0 = *reinterpret_cast<const float4*>(&att[cb]);
        float4 w1 = *reinterpret_cast<const float4*>(&att[cb + 4]);
        float aa[8] = {w0.x, w0.y, w0.z, w0.w, w1.x, w1.y, w1.z, w1.w};
        #pragma unroll
        for (int c = 0; c < 8; ++c) { a6[c] = 0.6f * aa[c]; a4[c] = 0.4f * aa[c]; }
    }

    float acc[8], l, m;
    {
        float4 u0 = *reinterpret_cast<const float4*>(&xl[(size_t)i * 128 + cb]);
        float4 u1 = *reinterpret_cast<const float4*>(&xl[(size_t)i * 128 + cb + 4]);
        float u[8] = {u0.x, u0.y, u0.z, u0.w, u1.x, u1.y, u1.z, u1.w};
        float p = 0.f;
        #pragma unroll
        for (int c = 0; c < 8; ++c) {
            float v = u[c] + rxr[c];
            p = fmaf(a6[c], v, p);
            p = fmaf(a4[c], fabsf(v), p);
        }
        p += __shfl_xor(p, 1, 8);
        p += __shfl_xor(p, 2, 8);
        p += __shfl_xor(p, 4, 8);
        m = p;
        l = es ? 0.f : 1.f;
        #pragma unroll
        for (int c = 0; c < 8; ++c) acc[c] = es ? 0.f : u[c];
    }

    int start = row_ptr[i], end = row_ptr[i + 1];
    for (int k = start; k < end; k += 8) {
        int kk = k + es;
        int s = (kk < end) ? csr[kk] : i;
        float4 u0 = *reinterpret_cast<const float4*>(&xl[(size_t)s * 128 + cb]);
        float4 u1 = *reinterpret_cast<const float4*>(&xl[(size_t)s * 128 + cb + 4]);
        float u[8] = {u0.x, u0.y, u0.z, u0.w, u1.x, u1.y, u1.z, u1.w};
        float p = 0.f;
        #pragma unroll
        for (int c = 0; c < 8; ++c) {
            float v = u[c] + rxr[c];
            p = fmaf(a6[c], v, p);
            p = fmaf(a4[c], fabsf(v), p);
        }
        p += __shfl_xor(p, 1, 8);
        p += __shfl_xor(p, 2, 8);
        p += __shfl_xor(p, 4, 8);
        float e = (kk < end) ? __expf(fminf(p - m, 60.f)) : 0.f;
        l += e;
        #pragma unroll
        for (int c = 0; c < 8; ++c) acc[c] = fmaf(e, u[c], acc[c]);
    }

    l += __shfl_xor(l, 8, 64);
    l += __shfl_xor(l, 16, 64);
    l += __shfl_xor(l, 32, 64);
    #pragma unroll
    for (int c = 0; c < 8; ++c) {
        acc[c] += __shfl_xor(acc[c], 8, 64);
        acc[c] += __shfl_xor(acc[c], 16, 64);
        acc[c] += __shfl_xor(acc[c], 32, 64);
    }

    if (es == 0) {
        float inv = 1.0f / l;
        float4 bb0 = *reinterpret_cast<const float4*>(&bias[cb]);
        float4 bb1 = *reinterpret_cast<const float4*>(&bias[cb + 4]);
        float4 o0, o1;
        o0.x = fmaf(acc[0], inv, bb0.x);
        o0.y = fmaf(acc[1], inv, bb0.y);
        o0.z = fmaf(acc[2], inv, bb0.z);
        o0.w = fmaf(acc[3], inv, bb0.w);
        o1.x = fmaf(acc[4], inv, bb1.x);
        o1.y = fmaf(acc[5], inv, bb1.y);
        o1.z = fmaf(acc[6], inv, bb1.z);
        o1.w = fmaf(acc[7], inv, bb1.w);
        *reinterpret_cast<float4*>(&out[(size_t)i * 64 + cb]) = o0;
        *reinterpret_cast<float4*>(&out[(size_t)i * 64 + cb + 4]) = o1;
    }
}

// ---------------------------------------------------------------------------

extern "C" void kernel_launch(void* const* d_in, const int* in_sizes, int n_in,
                              void* d_out, int out_size, void* d_ws, size_t ws_size,
                              hipStream_t stream) {
    const float* x    = (const float*)d_in[0];
    const void*  ei   = d_in[1];
    const float* Wl1  = (const float*)d_in[2];
    const float* Wr1  = (const float*)d_in[3];
    const float* att1 = (const float*)d_in[4];
    const float* b1   = (const float*)d_in[5];
    const float* Wl2  = (const float*)d_in[6];
    const float* Wr2  = (const float*)d_in[7];
    const float* att2 = (const float*)d_in[8];
    const float* b2   = (const float*)d_in[9];
    const float* Wl3  = (const float*)d_in[10];
    const float* Wr3  = (const float*)d_in[11];
    const float* att3 = (const float*)d_in[12];
    const float* b3   = (const float*)d_in[13];
    float* out = (float*)d_out;

    int N = in_sizes[0] / 256;
    int E = in_sizes[1] / 2;

    char* w = (char*)d_ws;
    unsigned short* h_hi = (unsigned short*)w; w += (size_t)N * 256 * 2;
    unsigned short* h_lo = (unsigned short*)w; w += (size_t)N * 256 * 2;
    float* C = (float*)w;          w += (size_t)N * 512 * sizeof(float);
    unsigned short* WT_hi = (unsigned short*)w; w += (size_t)512 * 256 * 2;
    unsigned short* WT_lo = (unsigned short*)w; w += (size_t)512 * 256 * 2;
    int* row_ptr = (int*)w; w += ((size_t)N + 2) * sizeof(int);
    int* deg     = (int*)w; w += (size_t)N * sizeof(int);
    int* csr     = (int*)w; w += (size_t)E * sizeof(int);
    int* flag    = (int*)w; w += 256;
    int* partial = (int*)w; w += 256;

    // --- CSR build ---
    detect_i64_kernel<<<1, 256, 0, stream>>>((const unsigned int*)ei, E, flag);
    fill_zero_kernel<<<(N + 255) / 256, 256, 0, stream>>>(deg, N);
    count_deg_kernel<<<(E + 255) / 256, 256, 0, stream>>>(ei, E, flag, deg);
    int nb = (N + 1023) / 1024;
    scan_block_kernel<<<nb, 1024, 0, stream>>>(deg, row_ptr, partial, N);
    scan_top_kernel<<<1, 64, 0, stream>>>(partial, nb);
    scan_addoff_kernel<<<(N + 255) / 256, 256, 0, stream>>>(row_ptr, partial, N);
    fill_zero_kernel<<<(N + 255) / 256, 256, 0, stream>>>(deg, N);
    scatter_kernel<<<(E + 255) / 256, 256, 0, stream>>>(ei, E, flag, row_ptr, deg, csr);

    int gemm_gx = (N + 127) / 128;
    int agg_g = (N + 3) / 4;

    // --- Layer 1 ---
    split_kernel<<<((N * 256 / 4) + 255) / 256, 256, 0, stream>>>(x, N * 256 / 4, h_hi, h_lo);
    splitT_w_kernel<<<dim3(256, 2), 256, 0, stream>>>(Wl1, Wr1, 256, WT_hi, WT_lo);
    gemm_mfma_kernel<<<dim3(gemm_gx, 4), 256, 0, stream>>>(h_hi, h_lo, WT_hi, WT_lo, C, N, 512);
    agg_h8_kernel<<<agg_g, 256, 0, stream>>>(C, 512, att1, b1, row_ptr, csr, h_hi, h_lo, N);

    // --- Layer 2 ---
    splitT_w_kernel<<<dim3(256, 2), 256, 0, stream>>>(Wl2, Wr2, 256, WT_hi, WT_lo);
    gemm_mfma_kernel<<<dim3(gemm_gx, 4), 256, 0, stream>>>(h_hi, h_lo, WT_hi, WT_lo, C, N, 512);
    agg_h8_kernel<<<agg_g, 256, 0, stream>>>(C, 512, att2, b2, row_ptr, csr, h_hi, h_lo, N);

    // --- Layer 3 ---
    splitT_w_kernel<<<dim3(256, 1), 256, 0, stream>>>(Wl3, Wr3, 64, WT_hi, WT_lo);
    gemm_mfma_kernel<<<dim3(gemm_gx, 1), 256, 0, stream>>>(h_hi, h_lo, WT_hi, WT_lo, C, N, 128);
    agg_h1_kernel<<<agg_g, 256, 0, stream>>>(C, att3, b3, row_ptr, csr, out, N);
}

// Round 6
// 556.776 us; speedup vs baseline: 2.1516x; 1.0101x over previous
//
#include <hip/hip_runtime.h>

#define NEG_SLOPE 0.2f

typedef __attribute__((ext_vector_type(8))) short bf16x8;
typedef __attribute__((ext_vector_type(4))) float f32x4;

__device__ __forceinline__ unsigned short f2bf_rne(float x) {
    unsigned int u = __float_as_uint(x);
    unsigned int r = (u + 0x7FFFu + ((u >> 16) & 1u)) >> 16;
    return (unsigned short)r;
}

__device__ __forceinline__ void gload_lds16(const unsigned short* g, unsigned short* lds) {
    __builtin_amdgcn_global_load_lds(
        (const __attribute__((address_space(1))) void*)g,
        (__attribute__((address_space(3))) void*)lds, 16, 0, 0);
}

// ---------------------------------------------------------------------------
// CSR build
// ---------------------------------------------------------------------------

__global__ void fill_zero_kernel(int* __restrict__ p, int n) {
    int i = blockIdx.x * blockDim.x + threadIdx.x;
    if (i < n) p[i] = 0;
}

__global__ void detect_i64_kernel(const unsigned int* __restrict__ w, int E, int* __restrict__ flag) {
    __shared__ unsigned int ssum[256];
    int n = E < 4096 ? E : 4096;
    unsigned int local = 0;
    for (int k = threadIdx.x; k < n; k += 256) local |= w[2 * k + 1];
    ssum[threadIdx.x] = local;
    __syncthreads();
    for (int off = 128; off > 0; off >>= 1) {
        if (threadIdx.x < off) ssum[threadIdx.x] |= ssum[threadIdx.x + off];
        __syncthreads();
    }
    if (threadIdx.x == 0) flag[0] = (ssum[0] == 0) ? 1 : 0;
}

__global__ void count_deg_kernel(const void* __restrict__ eiv, int E,
                                 const int* __restrict__ flag, int* __restrict__ deg) {
    int e = blockIdx.x * blockDim.x + threadIdx.x;
    if (e >= E) return;
    int d;
    if (*flag) d = (int)((const long long*)eiv)[(size_t)E + e];
    else       d = ((const int*)eiv)[(size_t)E + e];
    atomicAdd(&deg[d], 1);
}

__global__ void scan_block_kernel(const int* __restrict__ deg, int* __restrict__ row_ptr,
                                  int* __restrict__ partial, int N) {
    __shared__ int sd[1024];
    int t = threadIdx.x;
    int g = blockIdx.x * 1024 + t;
    int v = (g < N) ? deg[g] : 0;
    sd[t] = v;
    __syncthreads();
    for (int off = 1; off < 1024; off <<= 1) {
        int add = (t >= off) ? sd[t - off] : 0;
        __syncthreads();
        sd[t] += add;
        __syncthreads();
    }
    if (g < N) row_ptr[g + 1] = sd[t];
    if (t == 1023) partial[blockIdx.x] = sd[1023];
    if (g == 0) row_ptr[0] = 0;
}

__global__ void scan_top_kernel(int* __restrict__ partial, int nb) {
    if (threadIdx.x == 0 && blockIdx.x == 0) {
        int run = 0;
        for (int j = 0; j < nb; ++j) { run += partial[j]; partial[j] = run; }
    }
}

__global__ void scan_addoff_kernel(int* __restrict__ row_ptr, const int* __restrict__ partial, int N) {
    int g = blockIdx.x * 256 + threadIdx.x;
    if (g >= N) return;
    int b = g >> 10;
    if (b > 0) row_ptr[g + 1] += partial[b - 1];
}

__global__ void scatter_kernel(const void* __restrict__ eiv, int E,
                               const int* __restrict__ flag,
                               const int* __restrict__ row_ptr,
                               int* __restrict__ cursor, int* __restrict__ csr) {
    int e = blockIdx.x * blockDim.x + threadIdx.x;
    if (e >= E) return;
    int s, d;
    if (*flag) {
        s = (int)((const long long*)eiv)[e];
        d = (int)((const long long*)eiv)[(size_t)E + e];
    } else {
        s = ((const int*)eiv)[e];
        d = ((const int*)eiv)[(size_t)E + e];
    }
    int pos = atomicAdd(&cursor[d], 1);
    csr[row_ptr[d] + pos] = s;
}

// ---------------------------------------------------------------------------
// fp32 -> bf16 hi/lo split
// ---------------------------------------------------------------------------

__global__ void split_kernel(const float* __restrict__ src, int n4,
                             unsigned short* __restrict__ hi, unsigned short* __restrict__ lo) {
    int i = blockIdx.x * blockDim.x + threadIdx.x;
    if (i >= n4) return;
    float4 v = *reinterpret_cast<const float4*>(&src[(size_t)i * 4]);
    ushort4 h, l;
    float f;
    h.x = f2bf_rne(v.x); f = v.x - __uint_as_float((unsigned int)h.x << 16); l.x = f2bf_rne(f);
    h.y = f2bf_rne(v.y); f = v.y - __uint_as_float((unsigned int)h.y << 16); l.y = f2bf_rne(f);
    h.z = f2bf_rne(v.z); f = v.z - __uint_as_float((unsigned int)h.z << 16); l.z = f2bf_rne(f);
    h.w = f2bf_rne(v.w); f = v.w - __uint_as_float((unsigned int)h.w << 16); l.w = f2bf_rne(f);
    *reinterpret_cast<ushort4*>(&hi[(size_t)i * 4]) = h;
    *reinterpret_cast<ushort4*>(&lo[(size_t)i * 4]) = l;
}

__global__ void splitT_w_kernel(const float* __restrict__ Wl, const float* __restrict__ Wr, int M,
                                unsigned short* __restrict__ WThi, unsigned short* __restrict__ WTlo) {
    int k = blockIdx.x;
    int m2 = blockIdx.y * 256 + threadIdx.x;
    if (m2 >= 2 * M) return;
    float v = (m2 < M) ? Wl[(size_t)k * M + m2] : Wr[(size_t)k * M + (m2 - M)];
    unsigned short h = f2bf_rne(v);
    float fl = v - __uint_as_float((unsigned int)h << 16);
    WThi[(size_t)m2 * 256 + k] = h;
    WTlo[(size_t)m2 * 256 + k] = f2bf_rne(fl);
}

// ---------------------------------------------------------------------------
// MFMA GEMM (split-bf16, 3 passes), tile 128x128, BK=64.
// Staging via global_load_lds (direct-to-LDS, 16B/lane) with PRE-SWIZZLED
// global source: lane (r8=lane>>3, c8=lane&7) loads global k-chunk c8^r8 so
// the linear LDS write produces the XOR-swizzled layout the compute phase
// expects (lds pos p of row r holds global chunk p^(r&7)).
// ---------------------------------------------------------------------------

__global__ __launch_bounds__(256) void gemm_mfma_kernel(
    const unsigned short* __restrict__ Ahi, const unsigned short* __restrict__ Alo,
    const unsigned short* __restrict__ Bhi, const unsigned short* __restrict__ Blo,
    float* __restrict__ C, int N, int ldc) {
    __shared__ unsigned short sA[2][128 * 64];
    __shared__ unsigned short sB[2][128 * 64];

    int t = threadIdx.x;
    int lane = t & 63;
    int w = t >> 6;
    int wr = (w >> 1) * 64;
    int wc = (w & 1) * 64;
    int row0 = blockIdx.x * 128;
    int n0 = blockIdx.y * 128;

    int l15 = lane & 15;
    int l4 = lane >> 4;

    int lr8 = lane >> 3;      // row within 8-row group
    int lc8 = lane & 7;       // chunk position
    int ksw = (lc8 ^ lr8) * 8;  // pre-swizzled source k-offset (ushorts)

    f32x4 acc[4][4] = {};

    for (int k0 = 0; k0 < 256; k0 += 64) {
        __syncthreads();
        #pragma unroll
        for (int i = 0; i < 4; ++i) {
            int brow = i * 32 + w * 8;          // wave-uniform base row
            int row = brow + lr8;
            int ar = row0 + row; if (ar >= N) ar = N - 1;
            int bc = n0 + row;
            gload_lds16(&Ahi[(size_t)ar * 256 + k0 + ksw], &sA[0][brow * 64]);
            gload_lds16(&Alo[(size_t)ar * 256 + k0 + ksw], &sA[1][brow * 64]);
            gload_lds16(&Bhi[(size_t)bc * 256 + k0 + ksw], &sB[0][brow * 64]);
            gload_lds16(&Blo[(size_t)bc * 256 + k0 + ksw], &sB[1][brow * 64]);
        }
        __syncthreads();

        #pragma unroll
        for (int ksub = 0; ksub < 2; ++ksub) {
            int kb = ksub * 32 + l4 * 8;
            bf16x8 bh[4], bl[4];
            #pragma unroll
            for (int fc = 0; fc < 4; ++fc) {
                int c = wc + fc * 16 + l15;
                int idx = c * 64 + (kb ^ ((c & 7) << 3));
                bh[fc] = *reinterpret_cast<const bf16x8*>(&sB[0][idx]);
                bl[fc] = *reinterpret_cast<const bf16x8*>(&sB[1][idx]);
            }
            #pragma unroll
            for (int fr = 0; fr < 4; ++fr) {
                int r = wr + fr * 16 + l15;
                int idx = r * 64 + (kb ^ ((r & 7) << 3));
                bf16x8 ah = *reinterpret_cast<const bf16x8*>(&sA[0][idx]);
                bf16x8 al = *reinterpret_cast<const bf16x8*>(&sA[1][idx]);
                #pragma unroll
                for (int fc = 0; fc < 4; ++fc) {
                    acc[fr][fc] = __builtin_amdgcn_mfma_f32_16x16x32_bf16(ah, bh[fc], acc[fr][fc], 0, 0, 0);
                    acc[fr][fc] = __builtin_amdgcn_mfma_f32_16x16x32_bf16(ah, bl[fc], acc[fr][fc], 0, 0, 0);
                    acc[fr][fc] = __builtin_amdgcn_mfma_f32_16x16x32_bf16(al, bh[fc], acc[fr][fc], 0, 0, 0);
                }
            }
        }
    }

    #pragma unroll
    for (int fr = 0; fr < 4; ++fr) {
        #pragma unroll
        for (int j = 0; j < 4; ++j) {
            int row = row0 + wr + fr * 16 + l4 * 4 + j;
            if (row < N) {
                #pragma unroll
                for (int fc = 0; fc < 4; ++fc) {
                    int col = n0 + wc + fc * 16 + l15;
                    C[(size_t)row * ldc + col] = acc[fr][fc][j];
                }
            }
        }
    }
}

// ---------------------------------------------------------------------------
// agg_h8 v5: one wave per node; half = lane>>5 picks edge slot, lane&31 owns
// 8 channels. Fixed-m softmax (m = self logit). 1-deep software pipeline:
// next iteration's indices + gathers issued before computing current.
// ---------------------------------------------------------------------------

__global__ __launch_bounds__(256) void agg_h8_kernel(
    const float* __restrict__ Cin, int ld,
    const float* __restrict__ att, const float* __restrict__ bias,
    const int* __restrict__ row_ptr, const int* __restrict__ csr,
    unsigned short* __restrict__ ohi, unsigned short* __restrict__ olo, int N) {
    int wv = threadIdx.x >> 6;
    int i = blockIdx.x * 4 + wv;
    if (i >= N) return;
    int lane = threadIdx.x & 63;
    int half = lane >> 5;
    int cb = (lane & 31) * 8;
    const float* xl = Cin;
    const float* xr = Cin + (ld >> 1);

    float rxr[8], a6[8], a4[8];
    {
        float4 r0 = *reinterpret_cast<const float4*>(&xr[(size_t)i * ld + cb]);
        float4 r1 = *reinterpret_cast<const float4*>(&xr[(size_t)i * ld + cb + 4]);
        rxr[0] = r0.x; rxr[1] = r0.y; rxr[2] = r0.z; rxr[3] = r0.w;
        rxr[4] = r1.x; rxr[5] = r1.y; rxr[6] = r1.z; rxr[7] = r1.w;
        float4 w0 = *reinterpret_cast<const float4*>(&att[cb]);
        float4 w1 = *reinterpret_cast<const float4*>(&att[cb + 4]);
        float aa[8] = {w0.x, w0.y, w0.z, w0.w, w1.x, w1.y, w1.z, w1.w};
        #pragma unroll
        for (int c = 0; c < 8; ++c) { a6[c] = 0.6f * aa[c]; a4[c] = 0.4f * aa[c]; }
    }

    float acc[8], l, m;
    {
        float4 u0 = *reinterpret_cast<const float4*>(&xl[(size_t)i * ld + cb]);
        float4 u1 = *reinterpret_cast<const float4*>(&xl[(size_t)i * ld + cb + 4]);
        float u[8] = {u0.x, u0.y, u0.z, u0.w, u1.x, u1.y, u1.z, u1.w};
        float p = 0.f;
        #pragma unroll
        for (int c = 0; c < 8; ++c) {
            float v = u[c] + rxr[c];
            p = fmaf(a6[c], v, p);
            p = fmaf(a4[c], fabsf(v), p);
        }
        p += __shfl_xor(p, 1, 4);
        p += __shfl_xor(p, 2, 4);
        m = p;
        l = half ? 0.f : 1.f;
        #pragma unroll
        for (int c = 0; c < 8; ++c) acc[c] = half ? 0.f : u[c];
    }

    int start = row_ptr[i], end = row_ptr[i + 1];

    // pipeline prologue: load iteration 0
    int kk0 = start + half, kk1 = start + 2 + half;
    int s0 = (kk0 < end) ? csr[kk0] : i;
    int s1 = (kk1 < end) ? csr[kk1] : i;
    float4 ca0 = *reinterpret_cast<const float4*>(&xl[(size_t)s0 * ld + cb]);
    float4 ca1 = *reinterpret_cast<const float4*>(&xl[(size_t)s0 * ld + cb + 4]);
    float4 cb0 = *reinterpret_cast<const float4*>(&xl[(size_t)s1 * ld + cb]);
    float4 cb1 = *reinterpret_cast<const float4*>(&xl[(size_t)s1 * ld + cb + 4]);

    for (int k = start; k < end; k += 4) {
        // issue next iteration's loads before computing current
        int nk0 = k + 4 + half, nk1 = k + 6 + half;
        int t0 = (nk0 < end) ? csr[nk0] : i;
        int t1 = (nk1 < end) ? csr[nk1] : i;
        float4 na0 = *reinterpret_cast<const float4*>(&xl[(size_t)t0 * ld + cb]);
        float4 na1 = *reinterpret_cast<const float4*>(&xl[(size_t)t0 * ld + cb + 4]);
        float4 nb0 = *reinterpret_cast<const float4*>(&xl[(size_t)t1 * ld + cb]);
        float4 nb1 = *reinterpret_cast<const float4*>(&xl[(size_t)t1 * ld + cb + 4]);

        float ua[8] = {ca0.x, ca0.y, ca0.z, ca0.w, ca1.x, ca1.y, ca1.z, ca1.w};
        float ub[8] = {cb0.x, cb0.y, cb0.z, cb0.w, cb1.x, cb1.y, cb1.z, cb1.w};
        float p0 = 0.f, p1 = 0.f;
        #pragma unroll
        for (int c = 0; c < 8; ++c) {
            float v0 = ua[c] + rxr[c];
            p0 = fmaf(a6[c], v0, p0);
            p0 = fmaf(a4[c], fabsf(v0), p0);
            float v1 = ub[c] + rxr[c];
            p1 = fmaf(a6[c], v1, p1);
            p1 = fmaf(a4[c], fabsf(v1), p1);
        }
        p0 += __shfl_xor(p0, 1, 4);
        p0 += __shfl_xor(p0, 2, 4);
        p1 += __shfl_xor(p1, 1, 4);
        p1 += __shfl_xor(p1, 2, 4);
        float e0 = (k + half < end)     ? __expf(fminf(p0 - m, 60.f)) : 0.f;
        float e1 = (k + 2 + half < end) ? __expf(fminf(p1 - m, 60.f)) : 0.f;
        l += e0 + e1;
        #pragma unroll
        for (int c = 0; c < 8; ++c) acc[c] = fmaf(e0, ua[c], fmaf(e1, ub[c], acc[c]));

        ca0 = na0; ca1 = na1; cb0 = nb0; cb1 = nb1;
    }

    l += __shfl_xor(l, 32, 64);
    #pragma unroll
    for (int c = 0; c < 8; ++c) acc[c] += __shfl_xor(acc[c], 32, 64);

    if (half == 0) {
        float4 bb0 = *reinterpret_cast<const float4*>(&bias[cb]);
        float4 bb1 = *reinterpret_cast<const float4*>(&bias[cb + 4]);
        float bs[8] = {bb0.x, bb0.y, bb0.z, bb0.w, bb1.x, bb1.y, bb1.z, bb1.w};
        float inv = 1.0f / l;
        unsigned int hw[4], lw[4];
        #pragma unroll
        for (int c2 = 0; c2 < 4; ++c2) {
            float r0 = fmaf(acc[2 * c2], inv, bs[2 * c2]);
            float r1 = fmaf(acc[2 * c2 + 1], inv, bs[2 * c2 + 1]);
            r0 = (r0 > 0.f) ? r0 : (__expf(r0) - 1.f);
            r1 = (r1 > 0.f) ? r1 : (__expf(r1) - 1.f);
            unsigned short h0 = f2bf_rne(r0), h1 = f2bf_rne(r1);
            float f0 = r0 - __uint_as_float((unsigned int)h0 << 16);
            float f1 = r1 - __uint_as_float((unsigned int)h1 << 16);
            unsigned short l0 = f2bf_rne(f0), l1 = f2bf_rne(f1);
            hw[c2] = (unsigned int)h0 | ((unsigned int)h1 << 16);
            lw[c2] = (unsigned int)l0 | ((unsigned int)l1 << 16);
        }
        *reinterpret_cast<uint4*>(&ohi[(size_t)i * 256 + cb]) = make_uint4(hw[0], hw[1], hw[2], hw[3]);
        *reinterpret_cast<uint4*>(&olo[(size_t)i * 256 + cb]) = make_uint4(lw[0], lw[1], lw[2], lw[3]);
    }
}

// ---------------------------------------------------------------------------
// agg_h1 v5 (layer 3): one wave per node, 8 edge slots x 8 lanes x 8 ch,
// fixed-m softmax, 1-deep pipeline.
// ---------------------------------------------------------------------------

__global__ __launch_bounds__(256) void agg_h1_kernel(
    const float* __restrict__ Cin,
    const float* __restrict__ att, const float* __restrict__ bias,
    const int* __restrict__ row_ptr, const int* __restrict__ csr,
    float* __restrict__ out, int N) {
    int wv = threadIdx.x >> 6;
    int i = blockIdx.x * 4 + wv;
    if (i >= N) return;
    int lane = threadIdx.x & 63;
    int es = lane >> 3;
    int cb = (lane & 7) * 8;
    const float* xl = Cin;
    const float* xr = Cin + 64;

    float rxr[8], a6[8], a4[8];
    {
        float4 r0 = *reinterpret_cast<const float4*>(&xr[(size_t)i * 128 + cb]);
        float4 r1 = *reinterpret_cast<const float4*>(&xr[(size_t)i * 128 + cb + 4]);
        rxr[0] = r0.x; rxr[1] = r0.y; rxr[2] = r0.z; rxr[3] = r0.w;
        rxr[4] = r1.x; rxr[5] = r1.y; rxr[6] = r1.z; rxr[7] = r1.w;
        float4 w0 = *reinterpret_cast<const float4*>(&att[cb]);
        float4 w1 = *reinterpret_cast<const float4*>(&att[cb + 4]);
        float aa[8] = {w0.x, w0.y, w0.z, w0.w, w1.x, w1.y, w1.z, w1.w};
        #pragma unroll
        for (int c = 0; c < 8; ++c) { a6[c] = 0.6f * aa[c]; a4[c] = 0.4f * aa[c]; }
    }

    float acc[8], l, m;
    {
        float4 u0 = *reinterpret_cast<const float4*>(&xl[(size_t)i * 128 + cb]);
        float4 u1 = *reinterpret_cast<const float4*>(&xl[(size_t)i * 128 + cb + 4]);
        float u[8] = {u0.x, u0.y, u0.z, u0.w, u1.x, u1.y, u1.z, u1.w};
        float p = 0.f;
        #pragma unroll
        for (int c = 0; c < 8; ++c) {
            float v = u[c] + rxr[c];
            p = fmaf(a6[c], v, p);
            p = fmaf(a4[c], fabsf(v), p);
        }
        p += __shfl_xor(p, 1, 8);
        p += __shfl_xor(p, 2, 8);
        p += __shfl_xor(p, 4, 8);
        m = p;
        l = es ? 0.f : 1.f;
        #pragma unroll
        for (int c = 0; c < 8; ++c) acc[c] = es ? 0.f : u[c];
    }

    int start = row_ptr[i], end = row_ptr[i + 1];

    int kk = start + es;
    int s = (kk < end) ? csr[kk] : i;
    float4 cu0 = *reinterpret_cast<const float4*>(&xl[(size_t)s * 128 + cb]);
    float4 cu1 = *reinterpret_cast<const float4*>(&xl[(size_t)s * 128 + cb + 4]);

    for (int k = start; k < end; k += 8) {
        int nk = k + 8 + es;
        int tn = (nk < end) ? csr[nk] : i;
        float4 nu0 = *reinterpret_cast<const float4*>(&xl[(size_t)tn * 128 + cb]);
        float4 nu1 = *reinterpret_cast<const float4*>(&xl[(size_t)tn * 128 + cb + 4]);

        float u[8] = {cu0.x, cu0.y, cu0.z, cu0.w, cu1.x, cu1.y, cu1.z, cu1.w};
        float p = 0.f;
        #pragma unroll
        for (int c = 0; c < 8; ++c) {
            float v = u[c] + rxr[c];
            p = fmaf(a6[c], v, p);
            p = fmaf(a4[c], fabsf(v), p);
        }
        p += __shfl_xor(p, 1, 8);
        p += __shfl_xor(p, 2, 8);
        p += __shfl_xor(p, 4, 8);
        float e = (k + es < end) ? __expf(fminf(p - m, 60.f)) : 0.f;
        l += e;
        #pragma unroll
        for (int c = 0; c < 8; ++c) acc[c] = fmaf(e, u[c], acc[c]);

        cu0 = nu0; cu1 = nu1;
    }

    l += __shfl_xor(l, 8, 64);
    l += __shfl_xor(l, 16, 64);
    l += __shfl_xor(l, 32, 64);
    #pragma unroll
    for (int c = 0; c < 8; ++c) {
        acc[c] += __shfl_xor(acc[c], 8, 64);
        acc[c] += __shfl_xor(acc[c], 16, 64);
        acc[c] += __shfl_xor(acc[c], 32, 64);
    }

    if (es == 0) {
        float inv = 1.0f / l;
        float4 bb0 = *reinterpret_cast<const float4*>(&bias[cb]);
        float4 bb1 = *reinterpret_cast<const float4*>(&bias[cb + 4]);
        float4 o0, o1;
        o0.x = fmaf(acc[0], inv, bb0.x);
        o0.y = fmaf(acc[1], inv, bb0.y);
        o0.z = fmaf(acc[2], inv, bb0.z);
        o0.w = fmaf(acc[3], inv, bb0.w);
        o1.x = fmaf(acc[4], inv, bb1.x);
        o1.y = fmaf(acc[5], inv, bb1.y);
        o1.z = fmaf(acc[6], inv, bb1.z);
        o1.w = fmaf(acc[7], inv, bb1.w);
        *reinterpret_cast<float4*>(&out[(size_t)i * 64 + cb]) = o0;
        *reinterpret_cast<float4*>(&out[(size_t)i * 64 + cb + 4]) = o1;
    }
}

// ---------------------------------------------------------------------------

extern "C" void kernel_launch(void* const* d_in, const int* in_sizes, int n_in,
                              void* d_out, int out_size, void* d_ws, size_t ws_size,
                              hipStream_t stream) {
    const float* x    = (const float*)d_in[0];
    const void*  ei   = d_in[1];
    const float* Wl1  = (const float*)d_in[2];
    const float* Wr1  = (const float*)d_in[3];
    const float* att1 = (const float*)d_in[4];
    const float* b1   = (const float*)d_in[5];
    const float* Wl2  = (const float*)d_in[6];
    const float* Wr2  = (const float*)d_in[7];
    const float* att2 = (const float*)d_in[8];
    const float* b2   = (const float*)d_in[9];
    const float* Wl3  = (const float*)d_in[10];
    const float* Wr3  = (const float*)d_in[11];
    const float* att3 = (const float*)d_in[12];
    const float* b3   = (const float*)d_in[13];
    float* out = (float*)d_out;

    int N = in_sizes[0] / 256;
    int E = in_sizes[1] / 2;

    char* w = (char*)d_ws;
    unsigned short* h_hi = (unsigned short*)w; w += (size_t)N * 256 * 2;
    unsigned short* h_lo = (unsigned short*)w; w += (size_t)N * 256 * 2;
    float* C = (float*)w;          w += (size_t)N * 512 * sizeof(float);
    unsigned short* WT_hi = (unsigned short*)w; w += (size_t)512 * 256 * 2;
    unsigned short* WT_lo = (unsigned short*)w; w += (size_t)512 * 256 * 2;
    int* row_ptr = (int*)w; w += ((size_t)N + 2) * sizeof(int);
    int* deg     = (int*)w; w += (size_t)N * sizeof(int);
    int* csr     = (int*)w; w += (size_t)E * sizeof(int);
    int* flag    = (int*)w; w += 256;
    int* partial = (int*)w; w += 256;

    // --- CSR build ---
    detect_i64_kernel<<<1, 256, 0, stream>>>((const unsigned int*)ei, E, flag);
    fill_zero_kernel<<<(N + 255) / 256, 256, 0, stream>>>(deg, N);
    count_deg_kernel<<<(E + 255) / 256, 256, 0, stream>>>(ei, E, flag, deg);
    int nb = (N + 1023) / 1024;
    scan_block_kernel<<<nb, 1024, 0, stream>>>(deg, row_ptr, partial, N);
    scan_top_kernel<<<1, 64, 0, stream>>>(partial, nb);
    scan_addoff_kernel<<<(N + 255) / 256, 256, 0, stream>>>(row_ptr, partial, N);
    fill_zero_kernel<<<(N + 255) / 256, 256, 0, stream>>>(deg, N);
    scatter_kernel<<<(E + 255) / 256, 256, 0, stream>>>(ei, E, flag, row_ptr, deg, csr);

    int gemm_gx = (N + 127) / 128;
    int agg_g = (N + 3) / 4;

    // --- Layer 1 ---
    split_kernel<<<((N * 256 / 4) + 255) / 256, 256, 0, stream>>>(x, N * 256 / 4, h_hi, h_lo);
    splitT_w_kernel<<<dim3(256, 2), 256, 0, stream>>>(Wl1, Wr1, 256, WT_hi, WT_lo);
    gemm_mfma_kernel<<<dim3(gemm_gx, 4), 256, 0, stream>>>(h_hi, h_lo, WT_hi, WT_lo, C, N, 512);
    agg_h8_kernel<<<agg_g, 256, 0, stream>>>(C, 512, att1, b1, row_ptr, csr, h_hi, h_lo, N);

    // --- Layer 2 ---
    splitT_w_kernel<<<dim3(256, 2), 256, 0, stream>>>(Wl2, Wr2, 256, WT_hi, WT_lo);
    gemm_mfma_kernel<<<dim3(gemm_gx, 4), 256, 0, stream>>>(h_hi, h_lo, WT_hi, WT_lo, C, N, 512);
    agg_h8_kernel<<<agg_g, 256, 0, stream>>>(C, 512, att2, b2, row_ptr, csr, h_hi, h_lo, N);

    // --- Layer 3 ---
    splitT_w_kernel<<<dim3(256, 1), 256, 0, stream>>>(Wl3, Wr3, 64, WT_hi, WT_lo);
    gemm_mfma_kernel<<<dim3(gemm_gx, 1), 256, 0, stream>>>(h_hi, h_lo, WT_hi, WT_lo, C, N, 128);
    agg_h1_kernel<<<agg_g, 256, 0, stream>>>(C, att3, b3, row_ptr, csr, out, N);
}

// Round 7
// 463.192 us; speedup vs baseline: 2.5863x; 1.2020x over previous
//
#include <hip/hip_runtime.h>
#include <hip/hip_fp16.h>

#define NEG_SLOPE 0.2f

typedef __attribute__((ext_vector_type(8))) short bf16x8;
typedef __attribute__((ext_vector_type(4))) float f32x4;

__device__ __forceinline__ unsigned short f2bf_rne(float x) {
    unsigned int u = __float_as_uint(x);
    unsigned int r = (u + 0x7FFFu + ((u >> 16) & 1u)) >> 16;
    return (unsigned short)r;
}

__device__ __forceinline__ void gload_lds16(const unsigned short* g, unsigned short* lds) {
    __builtin_amdgcn_global_load_lds(
        (const __attribute__((address_space(1))) void*)g,
        (__attribute__((address_space(3))) void*)lds, 16, 0, 0);
}

__device__ __forceinline__ void h8_to_f(const uint4 v, float* f) {
    const __half2* hp = reinterpret_cast<const __half2*>(&v);
    float2 t0 = __half22float2(hp[0]);
    float2 t1 = __half22float2(hp[1]);
    float2 t2 = __half22float2(hp[2]);
    float2 t3 = __half22float2(hp[3]);
    f[0] = t0.x; f[1] = t0.y; f[2] = t1.x; f[3] = t1.y;
    f[4] = t2.x; f[5] = t2.y; f[6] = t3.x; f[7] = t3.y;
}

// ---------------------------------------------------------------------------
// CSR build
// ---------------------------------------------------------------------------

__global__ void detect_i64_kernel(const unsigned int* __restrict__ w, int E, int* __restrict__ flag) {
    __shared__ unsigned int ssum[256];
    int n = E < 4096 ? E : 4096;
    unsigned int local = 0;
    for (int k = threadIdx.x; k < n; k += 256) local |= w[2 * k + 1];
    ssum[threadIdx.x] = local;
    __syncthreads();
    for (int off = 128; off > 0; off >>= 1) {
        if (threadIdx.x < off) ssum[threadIdx.x] |= ssum[threadIdx.x + off];
        __syncthreads();
    }
    if (threadIdx.x == 0) flag[0] = (ssum[0] == 0) ? 1 : 0;
}

__global__ void count_deg_kernel(const void* __restrict__ eiv, int E,
                                 const int* __restrict__ flag, int* __restrict__ deg) {
    int e = blockIdx.x * blockDim.x + threadIdx.x;
    if (e >= E) return;
    int d;
    if (*flag) d = (int)((const long long*)eiv)[(size_t)E + e];
    else       d = ((const int*)eiv)[(size_t)E + e];
    atomicAdd(&deg[d], 1);
}

__global__ void scan_block_kernel(const int* __restrict__ deg, int* __restrict__ row_ptr,
                                  int* __restrict__ partial, int N) {
    __shared__ int sd[1024];
    int t = threadIdx.x;
    int g = blockIdx.x * 1024 + t;
    int v = (g < N) ? deg[g] : 0;
    sd[t] = v;
    __syncthreads();
    for (int off = 1; off < 1024; off <<= 1) {
        int add = (t >= off) ? sd[t - off] : 0;
        __syncthreads();
        sd[t] += add;
        __syncthreads();
    }
    if (g < N) row_ptr[g + 1] = sd[t];
    if (t == 1023) partial[blockIdx.x] = sd[1023];
    if (g == 0) row_ptr[0] = 0;
}

__global__ void scan_top_kernel(int* __restrict__ partial, int nb) {
    if (threadIdx.x == 0 && blockIdx.x == 0) {
        int run = 0;
        for (int j = 0; j < nb; ++j) { run += partial[j]; partial[j] = run; }
    }
}

__global__ void scan_addoff_kernel(int* __restrict__ row_ptr, const int* __restrict__ partial, int N) {
    int g = blockIdx.x * 256 + threadIdx.x;
    if (g >= N) return;
    int b = g >> 10;
    if (b > 0) row_ptr[g + 1] += partial[b - 1];
}

__global__ void scatter_kernel(const void* __restrict__ eiv, int E,
                               const int* __restrict__ flag,
                               const int* __restrict__ row_ptr,
                               int* __restrict__ cursor, int* __restrict__ csr) {
    int e = blockIdx.x * blockDim.x + threadIdx.x;
    if (e >= E) return;
    int s, d;
    if (*flag) {
        s = (int)((const long long*)eiv)[e];
        d = (int)((const long long*)eiv)[(size_t)E + e];
    } else {
        s = ((const int*)eiv)[e];
        d = ((const int*)eiv)[(size_t)E + e];
    }
    int pos = atomicAdd(&cursor[d], 1);
    csr[row_ptr[d] + pos] = s;
}

// ---------------------------------------------------------------------------
// fp32 -> bf16 hi/lo split
// ---------------------------------------------------------------------------

__global__ void split_kernel(const float* __restrict__ src, int n4,
                             unsigned short* __restrict__ hi, unsigned short* __restrict__ lo) {
    int i = blockIdx.x * blockDim.x + threadIdx.x;
    if (i >= n4) return;
    float4 v = *reinterpret_cast<const float4*>(&src[(size_t)i * 4]);
    ushort4 h, l;
    float f;
    h.x = f2bf_rne(v.x); f = v.x - __uint_as_float((unsigned int)h.x << 16); l.x = f2bf_rne(f);
    h.y = f2bf_rne(v.y); f = v.y - __uint_as_float((unsigned int)h.y << 16); l.y = f2bf_rne(f);
    h.z = f2bf_rne(v.z); f = v.z - __uint_as_float((unsigned int)h.z << 16); l.z = f2bf_rne(f);
    h.w = f2bf_rne(v.w); f = v.w - __uint_as_float((unsigned int)h.w << 16); l.w = f2bf_rne(f);
    *reinterpret_cast<ushort4*>(&hi[(size_t)i * 4]) = h;
    *reinterpret_cast<ushort4*>(&lo[(size_t)i * 4]) = l;
}

__global__ void splitT_w_kernel(const float* __restrict__ Wl, const float* __restrict__ Wr, int M,
                                unsigned short* __restrict__ WThi, unsigned short* __restrict__ WTlo) {
    int k = blockIdx.x;
    int m2 = blockIdx.y * 256 + threadIdx.x;
    if (m2 >= 2 * M) return;
    float v = (m2 < M) ? Wl[(size_t)k * M + m2] : Wr[(size_t)k * M + (m2 - M)];
    unsigned short h = f2bf_rne(v);
    float fl = v - __uint_as_float((unsigned int)h << 16);
    WThi[(size_t)m2 * 256 + k] = h;
    WTlo[(size_t)m2 * 256 + k] = f2bf_rne(fl);
}

// ---------------------------------------------------------------------------
// MFMA GEMM (split-bf16, 3 passes), tile 128x128, BK=64, global_load_lds
// staging with pre-swizzled global source. Epilogue: logical cols [0,M) = xl
// -> fp16 buffer (gathered later), cols [M,2M) = xr -> fp32 buffer.
// ---------------------------------------------------------------------------

__global__ __launch_bounds__(256) void gemm_mfma_kernel(
    const unsigned short* __restrict__ Ahi, const unsigned short* __restrict__ Alo,
    const unsigned short* __restrict__ Bhi, const unsigned short* __restrict__ Blo,
    __half* __restrict__ xl16, float* __restrict__ xr32, int N, int M) {
    __shared__ unsigned short sA[2][128 * 64];
    __shared__ unsigned short sB[2][128 * 64];

    int t = threadIdx.x;
    int lane = t & 63;
    int w = t >> 6;
    int wr = (w >> 1) * 64;
    int wc = (w & 1) * 64;
    int row0 = blockIdx.x * 128;
    int n0 = blockIdx.y * 128;

    int l15 = lane & 15;
    int l4 = lane >> 4;

    int lr8 = lane >> 3;
    int lc8 = lane & 7;
    int ksw = (lc8 ^ lr8) * 8;

    f32x4 acc[4][4] = {};

    for (int k0 = 0; k0 < 256; k0 += 64) {
        __syncthreads();
        #pragma unroll
        for (int i = 0; i < 4; ++i) {
            int brow = i * 32 + w * 8;
            int row = brow + lr8;
            int ar = row0 + row; if (ar >= N) ar = N - 1;
            int bc = n0 + row;
            gload_lds16(&Ahi[(size_t)ar * 256 + k0 + ksw], &sA[0][brow * 64]);
            gload_lds16(&Alo[(size_t)ar * 256 + k0 + ksw], &sA[1][brow * 64]);
            gload_lds16(&Bhi[(size_t)bc * 256 + k0 + ksw], &sB[0][brow * 64]);
            gload_lds16(&Blo[(size_t)bc * 256 + k0 + ksw], &sB[1][brow * 64]);
        }
        __syncthreads();

        #pragma unroll
        for (int ksub = 0; ksub < 2; ++ksub) {
            int kb = ksub * 32 + l4 * 8;
            bf16x8 bh[4], bl[4];
            #pragma unroll
            for (int fc = 0; fc < 4; ++fc) {
                int c = wc + fc * 16 + l15;
                int idx = c * 64 + (kb ^ ((c & 7) << 3));
                bh[fc] = *reinterpret_cast<const bf16x8*>(&sB[0][idx]);
                bl[fc] = *reinterpret_cast<const bf16x8*>(&sB[1][idx]);
            }
            #pragma unroll
            for (int fr = 0; fr < 4; ++fr) {
                int r = wr + fr * 16 + l15;
                int idx = r * 64 + (kb ^ ((r & 7) << 3));
                bf16x8 ah = *reinterpret_cast<const bf16x8*>(&sA[0][idx]);
                bf16x8 al = *reinterpret_cast<const bf16x8*>(&sA[1][idx]);
                #pragma unroll
                for (int fc = 0; fc < 4; ++fc) {
                    acc[fr][fc] = __builtin_amdgcn_mfma_f32_16x16x32_bf16(ah, bh[fc], acc[fr][fc], 0, 0, 0);
                    acc[fr][fc] = __builtin_amdgcn_mfma_f32_16x16x32_bf16(ah, bl[fc], acc[fr][fc], 0, 0, 0);
                    acc[fr][fc] = __builtin_amdgcn_mfma_f32_16x16x32_bf16(al, bh[fc], acc[fr][fc], 0, 0, 0);
                }
            }
        }
    }

    #pragma unroll
    for (int fr = 0; fr < 4; ++fr) {
        #pragma unroll
        for (int j = 0; j < 4; ++j) {
            int row = row0 + wr + fr * 16 + l4 * 4 + j;
            if (row < N) {
                #pragma unroll
                for (int fc = 0; fc < 4; ++fc) {
                    int col = n0 + wc + fc * 16 + l15;
                    float v = acc[fr][fc][j];
                    if (col < M) xl16[(size_t)row * M + col] = __float2half(v);
                    else         xr32[(size_t)row * M + (col - M)] = v;
                }
            }
        }
    }
}

// ---------------------------------------------------------------------------
// agg_h8 v6: one wave per node; half = lane>>5 picks edge slot, lane&31 owns
// 8 channels. xl gathered as fp16 (one 16B load/lane/edge); xr read fp32 once.
// Fixed-m softmax (m = self logit), 1-deep pipeline.
// ---------------------------------------------------------------------------

__global__ __launch_bounds__(256) void agg_h8_kernel(
    const __half* __restrict__ xl16, const float* __restrict__ xr32,
    const float* __restrict__ att, const float* __restrict__ bias,
    const int* __restrict__ row_ptr, const int* __restrict__ csr,
    unsigned short* __restrict__ ohi, unsigned short* __restrict__ olo, int N) {
    int wv = threadIdx.x >> 6;
    int i = blockIdx.x * 4 + wv;
    if (i >= N) return;
    int lane = threadIdx.x & 63;
    int half = lane >> 5;
    int cb = (lane & 31) * 8;

    float rxr[8], a6[8], a4[8];
    {
        float4 r0 = *reinterpret_cast<const float4*>(&xr32[(size_t)i * 256 + cb]);
        float4 r1 = *reinterpret_cast<const float4*>(&xr32[(size_t)i * 256 + cb + 4]);
        rxr[0] = r0.x; rxr[1] = r0.y; rxr[2] = r0.z; rxr[3] = r0.w;
        rxr[4] = r1.x; rxr[5] = r1.y; rxr[6] = r1.z; rxr[7] = r1.w;
        float4 w0 = *reinterpret_cast<const float4*>(&att[cb]);
        float4 w1 = *reinterpret_cast<const float4*>(&att[cb + 4]);
        float aa[8] = {w0.x, w0.y, w0.z, w0.w, w1.x, w1.y, w1.z, w1.w};
        #pragma unroll
        for (int c = 0; c < 8; ++c) { a6[c] = 0.6f * aa[c]; a4[c] = 0.4f * aa[c]; }
    }

    float acc[8], l, m;
    {
        uint4 sv = *reinterpret_cast<const uint4*>(&xl16[(size_t)i * 256 + cb]);
        float u[8];
        h8_to_f(sv, u);
        float p = 0.f;
        #pragma unroll
        for (int c = 0; c < 8; ++c) {
            float v = u[c] + rxr[c];
            p = fmaf(a6[c], v, p);
            p = fmaf(a4[c], fabsf(v), p);
        }
        p += __shfl_xor(p, 1, 4);
        p += __shfl_xor(p, 2, 4);
        m = p;
        l = half ? 0.f : 1.f;
        #pragma unroll
        for (int c = 0; c < 8; ++c) acc[c] = half ? 0.f : u[c];
    }

    int start = row_ptr[i], end = row_ptr[i + 1];

    int kk0 = start + half, kk1 = start + 2 + half;
    int s0 = (kk0 < end) ? csr[kk0] : i;
    int s1 = (kk1 < end) ? csr[kk1] : i;
    uint4 ca = *reinterpret_cast<const uint4*>(&xl16[(size_t)s0 * 256 + cb]);
    uint4 cbv = *reinterpret_cast<const uint4*>(&xl16[(size_t)s1 * 256 + cb]);

    for (int k = start; k < end; k += 4) {
        int nk0 = k + 4 + half, nk1 = k + 6 + half;
        int t0 = (nk0 < end) ? csr[nk0] : i;
        int t1 = (nk1 < end) ? csr[nk1] : i;
        uint4 na = *reinterpret_cast<const uint4*>(&xl16[(size_t)t0 * 256 + cb]);
        uint4 nb = *reinterpret_cast<const uint4*>(&xl16[(size_t)t1 * 256 + cb]);

        float ua[8], ub[8];
        h8_to_f(ca, ua);
        h8_to_f(cbv, ub);
        float p0 = 0.f, p1 = 0.f;
        #pragma unroll
        for (int c = 0; c < 8; ++c) {
            float v0 = ua[c] + rxr[c];
            p0 = fmaf(a6[c], v0, p0);
            p0 = fmaf(a4[c], fabsf(v0), p0);
            float v1 = ub[c] + rxr[c];
            p1 = fmaf(a6[c], v1, p1);
            p1 = fmaf(a4[c], fabsf(v1), p1);
        }
        p0 += __shfl_xor(p0, 1, 4);
        p0 += __shfl_xor(p0, 2, 4);
        p1 += __shfl_xor(p1, 1, 4);
        p1 += __shfl_xor(p1, 2, 4);
        float e0 = (k + half < end)     ? __expf(fminf(p0 - m, 60.f)) : 0.f;
        float e1 = (k + 2 + half < end) ? __expf(fminf(p1 - m, 60.f)) : 0.f;
        l += e0 + e1;
        #pragma unroll
        for (int c = 0; c < 8; ++c) acc[c] = fmaf(e0, ua[c], fmaf(e1, ub[c], acc[c]));

        ca = na; cbv = nb;
    }

    l += __shfl_xor(l, 32, 64);
    #pragma unroll
    for (int c = 0; c < 8; ++c) acc[c] += __shfl_xor(acc[c], 32, 64);

    if (half == 0) {
        float4 bb0 = *reinterpret_cast<const float4*>(&bias[cb]);
        float4 bb1 = *reinterpret_cast<const float4*>(&bias[cb + 4]);
        float bs[8] = {bb0.x, bb0.y, bb0.z, bb0.w, bb1.x, bb1.y, bb1.z, bb1.w};
        float inv = 1.0f / l;
        unsigned int hw[4], lw[4];
        #pragma unroll
        for (int c2 = 0; c2 < 4; ++c2) {
            float r0 = fmaf(acc[2 * c2], inv, bs[2 * c2]);
            float r1 = fmaf(acc[2 * c2 + 1], inv, bs[2 * c2 + 1]);
            r0 = (r0 > 0.f) ? r0 : (__expf(r0) - 1.f);
            r1 = (r1 > 0.f) ? r1 : (__expf(r1) - 1.f);
            unsigned short h0 = f2bf_rne(r0), h1 = f2bf_rne(r1);
            float f0 = r0 - __uint_as_float((unsigned int)h0 << 16);
            float f1 = r1 - __uint_as_float((unsigned int)h1 << 16);
            unsigned short l0 = f2bf_rne(f0), l1 = f2bf_rne(f1);
            hw[c2] = (unsigned int)h0 | ((unsigned int)h1 << 16);
            lw[c2] = (unsigned int)l0 | ((unsigned int)l1 << 16);
        }
        *reinterpret_cast<uint4*>(&ohi[(size_t)i * 256 + cb]) = make_uint4(hw[0], hw[1], hw[2], hw[3]);
        *reinterpret_cast<uint4*>(&olo[(size_t)i * 256 + cb]) = make_uint4(lw[0], lw[1], lw[2], lw[3]);
    }
}

// ---------------------------------------------------------------------------
// agg_h1 v6 (layer 3): one wave per node, 8 edge slots x 8 lanes x 8 ch.
// xl gathered as fp16 (one 16B load/lane/edge). Fixed-m softmax, pipeline.
// ---------------------------------------------------------------------------

__global__ __launch_bounds__(256) void agg_h1_kernel(
    const __half* __restrict__ xl16, const float* __restrict__ xr32,
    const float* __restrict__ att, const float* __restrict__ bias,
    const int* __restrict__ row_ptr, const int* __restrict__ csr,
    float* __restrict__ out, int N) {
    int wv = threadIdx.x >> 6;
    int i = blockIdx.x * 4 + wv;
    if (i >= N) return;
    int lane = threadIdx.x & 63;
    int es = lane >> 3;
    int cb = (lane & 7) * 8;

    float rxr[8], a6[8], a4[8];
    {
        float4 r0 = *reinterpret_cast<const float4*>(&xr32[(size_t)i * 64 + cb]);
        float4 r1 = *reinterpret_cast<const float4*>(&xr32[(size_t)i * 64 + cb + 4]);
        rxr[0] = r0.x; rxr[1] = r0.y; rxr[2] = r0.z; rxr[3] = r0.w;
        rxr[4] = r1.x; rxr[5] = r1.y; rxr[6] = r1.z; rxr[7] = r1.w;
        float4 w0 = *reinterpret_cast<const float4*>(&att[cb]);
        float4 w1 = *reinterpret_cast<const float4*>(&att[cb + 4]);
        float aa[8] = {w0.x, w0.y, w0.z, w0.w, w1.x, w1.y, w1.z, w1.w};
        #pragma unroll
        for (int c = 0; c < 8; ++c) { a6[c] = 0.6f * aa[c]; a4[c] = 0.4f * aa[c]; }
    }

    float acc[8], l, m;
    {
        uint4 sv = *reinterpret_cast<const uint4*>(&xl16[(size_t)i * 64 + cb]);
        float u[8];
        h8_to_f(sv, u);
        float p = 0.f;
        #pragma unroll
        for (int c = 0; c < 8; ++c) {
            float v = u[c] + rxr[c];
            p = fmaf(a6[c], v, p);
            p = fmaf(a4[c], fabsf(v), p);
        }
        p += __shfl_xor(p, 1, 8);
        p += __shfl_xor(p, 2, 8);
        p += __shfl_xor(p, 4, 8);
        m = p;
        l = es ? 0.f : 1.f;
        #pragma unroll
        for (int c = 0; c < 8; ++c) acc[c] = es ? 0.f : u[c];
    }

    int start = row_ptr[i], end = row_ptr[i + 1];

    int kk = start + es;
    int s = (kk < end) ? csr[kk] : i;
    uint4 cu = *reinterpret_cast<const uint4*>(&xl16[(size_t)s * 64 + cb]);

    for (int k = start; k < end; k += 8) {
        int nk = k + 8 + es;
        int tn = (nk < end) ? csr[nk] : i;
        uint4 nu = *reinterpret_cast<const uint4*>(&xl16[(size_t)tn * 64 + cb]);

        float u[8];
        h8_to_f(cu, u);
        float p = 0.f;
        #pragma unroll
        for (int c = 0; c < 8; ++c) {
            float v = u[c] + rxr[c];
            p = fmaf(a6[c], v, p);
            p = fmaf(a4[c], fabsf(v), p);
        }
        p += __shfl_xor(p, 1, 8);
        p += __shfl_xor(p, 2, 8);
        p += __shfl_xor(p, 4, 8);
        float e = (k + es < end) ? __expf(fminf(p - m, 60.f)) : 0.f;
        l += e;
        #pragma unroll
        for (int c = 0; c < 8; ++c) acc[c] = fmaf(e, u[c], acc[c]);

        cu = nu;
    }

    l += __shfl_xor(l, 8, 64);
    l += __shfl_xor(l, 16, 64);
    l += __shfl_xor(l, 32, 64);
    #pragma unroll
    for (int c = 0; c < 8; ++c) {
        acc[c] += __shfl_xor(acc[c], 8, 64);
        acc[c] += __shfl_xor(acc[c], 16, 64);
        acc[c] += __shfl_xor(acc[c], 32, 64);
    }

    if (es == 0) {
        float inv = 1.0f / l;
        float4 bb0 = *reinterpret_cast<const float4*>(&bias[cb]);
        float4 bb1 = *reinterpret_cast<const float4*>(&bias[cb + 4]);
        float4 o0, o1;
        o0.x = fmaf(acc[0], inv, bb0.x);
        o0.y = fmaf(acc[1], inv, bb0.y);
        o0.z = fmaf(acc[2], inv, bb0.z);
        o0.w = fmaf(acc[3], inv, bb0.w);
        o1.x = fmaf(acc[4], inv, bb1.x);
        o1.y = fmaf(acc[5], inv, bb1.y);
        o1.z = fmaf(acc[6], inv, bb1.z);
        o1.w = fmaf(acc[7], inv, bb1.w);
        *reinterpret_cast<float4*>(&out[(size_t)i * 64 + cb]) = o0;
        *reinterpret_cast<float4*>(&out[(size_t)i * 64 + cb + 4]) = o1;
    }
}

// ---------------------------------------------------------------------------

extern "C" void kernel_launch(void* const* d_in, const int* in_sizes, int n_in,
                              void* d_out, int out_size, void* d_ws, size_t ws_size,
                              hipStream_t stream) {
    const float* x    = (const float*)d_in[0];
    const void*  ei   = d_in[1];
    const float* Wl1  = (const float*)d_in[2];
    const float* Wr1  = (const float*)d_in[3];
    const float* att1 = (const float*)d_in[4];
    const float* b1   = (const float*)d_in[5];
    const float* Wl2  = (const float*)d_in[6];
    const float* Wr2  = (const float*)d_in[7];
    const float* att2 = (const float*)d_in[8];
    const float* b2   = (const float*)d_in[9];
    const float* Wl3  = (const float*)d_in[10];
    const float* Wr3  = (const float*)d_in[11];
    const float* att3 = (const float*)d_in[12];
    const float* b3   = (const float*)d_in[13];
    float* out = (float*)d_out;

    int N = in_sizes[0] / 256;
    int E = in_sizes[1] / 2;

    char* w = (char*)d_ws;
    unsigned short* h_hi = (unsigned short*)w; w += (size_t)N * 256 * 2;
    unsigned short* h_lo = (unsigned short*)w; w += (size_t)N * 256 * 2;
    __half* xl16 = (__half*)w;     w += (size_t)N * 256 * 2;
    float* xr32 = (float*)w;       w += (size_t)N * 256 * sizeof(float);
    unsigned short* WT_hi = (unsigned short*)w; w += (size_t)512 * 256 * 2;
    unsigned short* WT_lo = (unsigned short*)w; w += (size_t)512 * 256 * 2;
    int* row_ptr = (int*)w; w += ((size_t)N + 2) * sizeof(int);
    int* deg     = (int*)w; w += (size_t)N * sizeof(int);
    int* csr     = (int*)w; w += (size_t)E * sizeof(int);
    int* flag    = (int*)w; w += 256;
    int* partial = (int*)w; w += 256;

    // --- CSR build ---
    detect_i64_kernel<<<1, 256, 0, stream>>>((const unsigned int*)ei, E, flag);
    hipMemsetAsync(deg, 0, (size_t)N * sizeof(int), stream);
    count_deg_kernel<<<(E + 255) / 256, 256, 0, stream>>>(ei, E, flag, deg);
    int nb = (N + 1023) / 1024;
    scan_block_kernel<<<nb, 1024, 0, stream>>>(deg, row_ptr, partial, N);
    scan_top_kernel<<<1, 64, 0, stream>>>(partial, nb);
    scan_addoff_kernel<<<(N + 255) / 256, 256, 0, stream>>>(row_ptr, partial, N);
    hipMemsetAsync(deg, 0, (size_t)N * sizeof(int), stream);
    scatter_kernel<<<(E + 255) / 256, 256, 0, stream>>>(ei, E, flag, row_ptr, deg, csr);

    int gemm_gx = (N + 127) / 128;
    int agg_g = (N + 3) / 4;

    // --- Layer 1 ---
    split_kernel<<<((N * 256 / 4) + 255) / 256, 256, 0, stream>>>(x, N * 256 / 4, h_hi, h_lo);
    splitT_w_kernel<<<dim3(256, 2), 256, 0, stream>>>(Wl1, Wr1, 256, WT_hi, WT_lo);
    gemm_mfma_kernel<<<dim3(gemm_gx, 4), 256, 0, stream>>>(h_hi, h_lo, WT_hi, WT_lo, xl16, xr32, N, 256);
    agg_h8_kernel<<<agg_g, 256, 0, stream>>>(xl16, xr32, att1, b1, row_ptr, csr, h_hi, h_lo, N);

    // --- Layer 2 ---
    splitT_w_kernel<<<dim3(256, 2), 256, 0, stream>>>(Wl2, Wr2, 256, WT_hi, WT_lo);
    gemm_mfma_kernel<<<dim3(gemm_gx, 4), 256, 0, stream>>>(h_hi, h_lo, WT_hi, WT_lo, xl16, xr32, N, 256);
    agg_h8_kernel<<<agg_g, 256, 0, stream>>>(xl16, xr32, att2, b2, row_ptr, csr, h_hi, h_lo, N);

    // --- Layer 3 ---
    splitT_w_kernel<<<dim3(256, 1), 256, 0, stream>>>(Wl3, Wr3, 64, WT_hi, WT_lo);
    gemm_mfma_kernel<<<dim3(gemm_gx, 1), 256, 0, stream>>>(h_hi, h_lo, WT_hi, WT_lo, xl16, xr32, N, 64);
    agg_h1_kernel<<<agg_g, 256, 0, stream>>>(xl16, xr32, att3, b3, row_ptr, csr, out, N);
}